// Round 1
// baseline (805.767 us; speedup 1.0000x reference)
//
#include <hip/hip_runtime.h>

typedef unsigned short u16;
typedef short bf16x8 __attribute__((ext_vector_type(8)));
typedef float f32x4 __attribute__((ext_vector_type(4)));

#define S_LEN 2048
#define ATT_SCALE 0.08838834764831845f
#define NEG_BIG  -1.0e30f

static __device__ __forceinline__ float bf2f(u16 u) {
  union { unsigned int i; float f; } v; v.i = ((unsigned int)u) << 16; return v.f;
}
static __device__ __forceinline__ u16 f2bf(float f) {
  union { float f; unsigned int i; } v; v.f = f;
  unsigned int x = v.i;
  return (u16)((x + 0x7fffu + ((x >> 16) & 1u)) >> 16);  // RNE
}

// async global->LDS, 16B per lane; lds dest = wave-uniform base + lane*16
static __device__ __forceinline__ void gl_lds16(const u16* g, u16* l) {
  __builtin_amdgcn_global_load_lds(
      (const __attribute__((address_space(1))) unsigned int*)g,
      (__attribute__((address_space(3))) unsigned int*)l, 16, 0, 0);
}

static __device__ __forceinline__ bf16x8 load8(const u16* p) { return *(const bf16x8*)p; }
static __device__ __forceinline__ bf16x8 load8(const float* p) {
  f32x4 a = *(const f32x4*)p;
  f32x4 b = *(const f32x4*)(p + 4);
  bf16x8 r;
  r[0] = (short)f2bf(a[0]); r[1] = (short)f2bf(a[1]);
  r[2] = (short)f2bf(a[2]); r[3] = (short)f2bf(a[3]);
  r[4] = (short)f2bf(b[0]); r[5] = (short)f2bf(b[1]);
  r[6] = (short)f2bf(b[2]); r[7] = (short)f2bf(b[3]);
  return r;
}
static __device__ __forceinline__ void store_out(u16* C, size_t i, float v)  { C[i] = f2bf(v); }
static __device__ __forceinline__ void store_out(float* C, size_t i, float v){ C[i] = v; }

// ---------------------------------------------------------------------------
// fp32 -> bf16 bulk convert (8 elems/thread)
// ---------------------------------------------------------------------------
__global__ __launch_bounds__(256) void f2b_kernel(
    const float* __restrict__ s, u16* __restrict__ d, int n8) {
  int i = blockIdx.x * 256 + threadIdx.x;
  if (i >= n8) return;
  *(bf16x8*)&d[(size_t)i * 8] = load8(s + (size_t)i * 8);
}

// ---------------------------------------------------------------------------
// m97-style bf16 GEMM core: C(M,N) = A(M,K)*B(N,K)^T.
// 128x128 tile, BK=64, global_load_lds width-16, XOR-swizzled unpadded LDS.
// ---------------------------------------------------------------------------
template <typename OT>
static __device__ __forceinline__ void gemm_core(
    const u16* __restrict__ A, const u16* __restrict__ B, OT* __restrict__ C,
    int K, int ldc, int bm, int bn) {
  __shared__ __align__(16) u16 As[128 * 64];
  __shared__ __align__(16) u16 Bs[128 * 64];
  const int tid  = threadIdx.x;
  const int lane = tid & 63;
  const int wave = tid >> 6;
  const int wm = (wave >> 1) << 6;
  const int wn = (wave & 1) << 6;
  const int col  = lane & 15;
  const int quad = lane >> 4;

  const f32x4 fzero = {0.f, 0.f, 0.f, 0.f};
  f32x4 acc[4][4];
#pragma unroll
  for (int i = 0; i < 4; ++i)
#pragma unroll
    for (int j = 0; j < 4; ++j) acc[i][j] = fzero;

  const int srow = (lane >> 3);
  const int sc8  = lane & 7;

  for (int k0 = 0; k0 < K; k0 += 64) {
#pragma unroll
    for (int i = 0; i < 4; ++i) {
      int r = wave * 32 + i * 8 + srow;
      int src = (sc8 ^ (r & 7)) << 3;
      gl_lds16(A + (size_t)(bm + r) * K + k0 + src, &As[(wave * 32 + i * 8) * 64]);
      gl_lds16(B + (size_t)(bn + r) * K + k0 + src, &Bs[(wave * 32 + i * 8) * 64]);
    }
    __syncthreads();
#pragma unroll
    for (int kk = 0; kk < 64; kk += 32) {
      bf16x8 af[4], bfr[4];
#pragma unroll
      for (int mt = 0; mt < 4; ++mt) {
        int row = wm + mt * 16 + col;
        af[mt] = *(const bf16x8*)&As[row * 64 + ((((kk >> 3) + quad) ^ (col & 7)) << 3)];
      }
#pragma unroll
      for (int nt = 0; nt < 4; ++nt) {
        int row = wn + nt * 16 + col;
        bfr[nt] = *(const bf16x8*)&Bs[row * 64 + ((((kk >> 3) + quad) ^ (col & 7)) << 3)];
      }
#pragma unroll
      for (int mt = 0; mt < 4; ++mt)
#pragma unroll
        for (int nt = 0; nt < 4; ++nt)
          acc[mt][nt] = __builtin_amdgcn_mfma_f32_16x16x32_bf16(
              af[mt], bfr[nt], acc[mt][nt], 0, 0, 0);
    }
    __syncthreads();
  }
#pragma unroll
  for (int mt = 0; mt < 4; ++mt)
#pragma unroll
    for (int nt = 0; nt < 4; ++nt)
#pragma unroll
      for (int r = 0; r < 4; ++r) {
        int row = bm + wm + mt * 16 + quad * 4 + r;
        int cn  = bn + wn + nt * 16 + col;
        store_out(C, (size_t)row * ldc + cn, acc[mt][nt][r]);
      }
}

__global__ __launch_bounds__(256) void gemm_qkv(
    const u16* __restrict__ xb, const u16* __restrict__ wqb,
    const u16* __restrict__ wkb, const u16* __restrict__ wvb,
    u16* __restrict__ q, u16* __restrict__ k, u16* __restrict__ v) {
  int bx = blockIdx.x;
  const u16* B; u16* C; int ldc, bn;
  if (bx < 32)      { B = wqb; C = q; ldc = 4096; bn = bx * 128; }
  else if (bx < 40) { B = wkb; C = k; ldc = 1024; bn = (bx - 32) * 128; }
  else              { B = wvb; C = v; ldc = 1024; bn = (bx - 40) * 128; }
  gemm_core<u16>(xb, B, C, 4096, ldc, blockIdx.y * 128, bn);
}

__global__ __launch_bounds__(256) void gemm_o(
    const u16* __restrict__ ao, const u16* __restrict__ wob, float* __restrict__ out) {
  gemm_core<float>(ao, wob, out, 4096, 4096, blockIdx.y * 128, blockIdx.x * 128);
}

// ---------------------------------------------------------------------------
// Fallback GEMM (fp32 staging convert, m93-class) for small workspace
// ---------------------------------------------------------------------------
#define LDK 72
template <typename AT, typename BT, typename OT>
__global__ __launch_bounds__(256) void gemm_bt(
    const AT* __restrict__ A, const BT* __restrict__ B,
    OT* __restrict__ C, int M, int N, int K) {
  __shared__ __align__(16) u16 As[128 * LDK];
  __shared__ __align__(16) u16 Bs[128 * LDK];
  const int tid  = threadIdx.x;
  const int lane = tid & 63;
  const int wave = tid >> 6;
  const int wm = (wave >> 1) << 6;
  const int wn = (wave & 1) << 6;
  const int col  = lane & 15;
  const int quad = lane >> 4;
  const int bm = blockIdx.y * 128;
  const int bn = blockIdx.x * 128;

  const f32x4 fzero = {0.f, 0.f, 0.f, 0.f};
  f32x4 acc[4][4];
#pragma unroll
  for (int i = 0; i < 4; ++i)
#pragma unroll
    for (int j = 0; j < 4; ++j) acc[i][j] = fzero;

  const int sr = tid >> 3;
  const int sc = (tid & 7) * 8;
  const AT* Aptr = A + (size_t)(bm + sr) * K + sc;
  const BT* Bptr = B + (size_t)(bn + sr) * K + sc;

  for (int k0 = 0; k0 < K; k0 += 64) {
#pragma unroll
    for (int p = 0; p < 4; ++p) {
      *(bf16x8*)&As[(sr + 32 * p) * LDK + sc] = load8(Aptr + (size_t)(32 * p) * K + k0);
      *(bf16x8*)&Bs[(sr + 32 * p) * LDK + sc] = load8(Bptr + (size_t)(32 * p) * K + k0);
    }
    __syncthreads();
#pragma unroll
    for (int kk = 0; kk < 64; kk += 32) {
      bf16x8 af[4], bfr[4];
#pragma unroll
      for (int mt = 0; mt < 4; ++mt)
        af[mt] = *(const bf16x8*)&As[(wm + mt * 16 + col) * LDK + kk + quad * 8];
#pragma unroll
      for (int nt = 0; nt < 4; ++nt)
        bfr[nt] = *(const bf16x8*)&Bs[(wn + nt * 16 + col) * LDK + kk + quad * 8];
#pragma unroll
      for (int mt = 0; mt < 4; ++mt)
#pragma unroll
        for (int nt = 0; nt < 4; ++nt)
          acc[mt][nt] = __builtin_amdgcn_mfma_f32_16x16x32_bf16(
              af[mt], bfr[nt], acc[mt][nt], 0, 0, 0);
    }
    __syncthreads();
  }
#pragma unroll
  for (int mt = 0; mt < 4; ++mt)
#pragma unroll
    for (int nt = 0; nt < 4; ++nt)
#pragma unroll
      for (int r = 0; r < 4; ++r) {
        int row = bm + wm + mt * 16 + quad * 4 + r;
        int cn  = bn + wn + nt * 16 + col;
        store_out(C, (size_t)row * N + cn, acc[mt][nt][r]);
      }
}

// ---------------------------------------------------------------------------
// RoPE in place on q (S,32,128) and k (S,8,128) bf16; scale folded into q.
// ---------------------------------------------------------------------------
__global__ __launch_bounds__(256) void rope_kernel(
    u16* __restrict__ q, u16* __restrict__ k,
    const float* __restrict__ cs, const float* __restrict__ sn) {
  int idx = blockIdx.x * 256 + threadIdx.x;
  const int QP = S_LEN * 32 * 64;
  u16* base;
  int s, i;
  bool isq = idx < QP;
  if (isq) {
    s = idx >> 11; int w = idx & 2047; i = w & 63;
    base = q + (size_t)s * 4096 + (w >> 6) * 128 + 2 * i;
  } else {
    int j = idx - QP;
    s = j >> 9; int w = j & 511; i = w & 63;
    base = k + (size_t)s * 1024 + (w >> 6) * 128 + 2 * i;
  }
  float c  = cs[s * 64 + i];
  float sv = sn[s * 64 + i];
  float x0 = bf2f(base[0]);
  float x1 = bf2f(base[1]);
  float r0 = x0 * c - x1 * sv;
  float r1 = x0 * sv + x1 * c;
  if (isq) { r0 *= ATT_SCALE; r1 *= ATT_SCALE; }
  base[0] = f2bf(r0);
  base[1] = f2bf(r1);
}

// ---------------------------------------------------------------------------
// Causal GQA flash attention, v4: paired q-tiles for perfect load balance.
// Block = (q-tiles {i, 31-i}, 1 head), 4 waves x 16 q-rows per tile.
// Both tiles share each staged KV chunk (one staging + one barrier pair
// serves both), so every block does exactly 33 tile-chunk units of MFMA.
// Grid (16, 32) = 512 blocks = 2 blocks/CU, no tail, no dispatch skew.
// ---------------------------------------------------------------------------
__global__ __launch_bounds__(256, 2) void attn_kernel(
    const u16* __restrict__ Q, const u16* __restrict__ K,
    const u16* __restrict__ V, u16* __restrict__ O) {
  const int ib   = blockIdx.x;       // 0..15
  const int qbA  = ib;               // light tile: chunks 0..ib
  const int qbB  = 31 - ib;          // heavy tile: chunks 0..31-ib
  const int h    = blockIdx.y;
  const int kvh  = h >> 2;
  const int tid  = threadIdx.x;
  const int lane = tid & 63;
  const int wave = tid >> 6;
  const int col  = lane & 15;
  const int quad = lane >> 4;

  __shared__ __align__(16) u16 Ks[64 * 128];  // [pos][hd], hd-chunks swizzled
  __shared__ __align__(16) u16 Vt[128 * 64];  // [hd][pos], pos-chunks swizzled

  const int qposA = qbA * 64 + wave * 16 + col;
  const int qposB = qbB * 64 + wave * 16 + col;

  // Q fragments (B-operand: n=q=lane&15, k=quad*8+j), 4 d-windows, both tiles
  bf16x8 qfA[4], qfB[4];
#pragma unroll
  for (int kb = 0; kb < 4; ++kb) {
    qfA[kb] = *(const bf16x8*)&Q[(size_t)qposA * 4096 + h * 128 + kb * 32 + quad * 8];
    qfB[kb] = *(const bf16x8*)&Q[(size_t)qposB * 4096 + h * 128 + kb * 32 + quad * 8];
  }

  const f32x4 fzero = {0.f, 0.f, 0.f, 0.f};
  // O^T accumulators: oacc[nt][r] at hd = nt*16 + quad*4 + r, q = col
  f32x4 oaccA[8], oaccB[8];
#pragma unroll
  for (int nt = 0; nt < 8; ++nt) { oaccA[nt] = fzero; oaccB[nt] = fzero; }
  float mA = NEG_BIG, lA = 0.f, mB = NEG_BIG, lB = 0.f;

  // staging indices
  const int krow = lane >> 4;        // K: row within 4-row issue
  const int kcnk = lane & 15;        // K: chunk slot 0..15
  const int vsc  = (tid & 15) * 8;   // V: hd group base
  const int vrp  = tid >> 4;         // V: pos-pair 0..15 (block-wide)
  const int vrot = tid & 7;

  int pos0 = 0;

  // one tile's worth of work against the currently staged KV chunk
  auto tile_step = [&](const bf16x8* qf, f32x4* oacc, float& m_, float& l_,
                       int qpos) {
    // ---- S^T = K Q^T : 4 kpos-tiles (m) x 1 q-tile (n) per wave
    f32x4 sv[4];
#pragma unroll
    for (int kv = 0; kv < 4; ++kv) sv[kv] = fzero;
#pragma unroll
    for (int kv = 0; kv < 4; ++kv) {
      int r = kv * 16 + col;
#pragma unroll
      for (int kb = 0; kb < 4; ++kb) {
        int kq = kb * 4 + quad;
        int slot = (kq & 8) | ((kq ^ r) & 7);
        bf16x8 kf = *(const bf16x8*)&Ks[r * 128 + slot * 8];
        sv[kv] = __builtin_amdgcn_mfma_f32_16x16x32_bf16(kf, qf[kb], sv[kv], 0, 0, 0);
      }
    }

    // ---- softmax over this lane's 16 values (q = col fixed) + quad-reduce
    float mx = NEG_BIG;
#pragma unroll
    for (int kv = 0; kv < 4; ++kv)
#pragma unroll
      for (int r = 0; r < 4; ++r) {
        float s = (pos0 + kv * 16 + quad * 4 + r) <= qpos ? sv[kv][r] : NEG_BIG;
        sv[kv][r] = s;
        mx = fmaxf(mx, s);
      }
    mx = fmaxf(mx, __shfl_xor(mx, 16));
    mx = fmaxf(mx, __shfl_xor(mx, 32));
    float mnew  = fmaxf(m_, mx);
    float alpha = __expf(m_ - mnew);
    float ls = 0.f;
#pragma unroll
    for (int kv = 0; kv < 4; ++kv)
#pragma unroll
      for (int r = 0; r < 4; ++r) {
        float p = __expf(sv[kv][r] - mnew);
        sv[kv][r] = p;
        ls += p;
      }
    ls += __shfl_xor(ls, 16);
    ls += __shfl_xor(ls, 32);
    l_ = l_ * alpha + ls;
    m_ = mnew;
#pragma unroll
    for (int nt = 0; nt < 8; ++nt) {
      oacc[nt][0] *= alpha; oacc[nt][1] *= alpha;
      oacc[nt][2] *= alpha; oacc[nt][3] *= alpha;
    }

    // pack P^T tiles: pk[kv][hh] = bf16x2(p[2hh], p[2hh+1])
    unsigned pk[4][2];
#pragma unroll
    for (int kv = 0; kv < 4; ++kv) {
      pk[kv][0] = (unsigned)f2bf(sv[kv][0]) | ((unsigned)f2bf(sv[kv][1]) << 16);
      pk[kv][1] = (unsigned)f2bf(sv[kv][2]) | ((unsigned)f2bf(sv[kv][3]) << 16);
    }

    // ---- O^T += V^T P^T, P B-frags built by in-register shuffle transpose
    const int idxA = col + 16 * (2 * (quad & 1));
    const int idxB = idxA + 16;
    const bool hi  = quad >= 2;
#pragma unroll
    for (int kc = 0; kc < 2; ++kc) {
      unsigned a00 = __shfl(pk[2 * kc][0],     idxA);
      unsigned a01 = __shfl(pk[2 * kc][1],     idxA);
      unsigned a10 = __shfl(pk[2 * kc + 1][0], idxA);
      unsigned a11 = __shfl(pk[2 * kc + 1][1], idxA);
      unsigned b00 = __shfl(pk[2 * kc][0],     idxB);
      unsigned b01 = __shfl(pk[2 * kc][1],     idxB);
      unsigned b10 = __shfl(pk[2 * kc + 1][0], idxB);
      unsigned b11 = __shfl(pk[2 * kc + 1][1], idxB);
      union { unsigned u[4]; bf16x8 v; } pb;
      pb.u[0] = hi ? a10 : a00;
      pb.u[1] = hi ? a11 : a01;
      pb.u[2] = hi ? b10 : b00;
      pb.u[3] = hi ? b11 : b01;
#pragma unroll
      for (int nt = 0; nt < 8; ++nt) {
        int hd = nt * 16 + col;
        int pc = kc * 4 + quad;
        bf16x8 vf = *(const bf16x8*)&Vt[hd * 64 + ((pc ^ (hd & 7)) << 3)];
        oacc[nt] = __builtin_amdgcn_mfma_f32_16x16x32_bf16(vf, pb.v, oacc[nt], 0, 0, 0);
      }
    }
  };

  const int nchunk = qbB + 1;            // heavy tile bounds the loop
  for (int c = 0; c < nchunk; ++c) {
    pos0 = c * 64;
    // ---- stage K via global_load_lds: wave stages rows wave*16..+15
#pragma unroll
    for (int i = 0; i < 4; ++i) {
      int r = wave * 16 + i * 4 + krow;
      int src = ((kcnk & 8) | ((kcnk ^ r) & 7)) << 3;
      gl_lds16(&K[(size_t)(pos0 + r) * 1024 + kvh * 128 + src],
               &Ks[(wave * 16 + i * 4) * 128]);
    }
    // ---- stage V^T: packed pos-pair b32 writes, swizzled pos-chunks
#pragma unroll
    for (int it = 0; it < 2; ++it) {
      int rp = vrp + it * 16;        // pos-pair 0..31
      const u16* vp = &V[(size_t)(pos0 + 2 * rp) * 1024 + kvh * 128 + vsc];
      union { bf16x8 v; u16 u[8]; } ue, uo;
      ue.v = *(const bf16x8*)vp;
      uo.v = *(const bf16x8*)(vp + 1024);
      int pc = rp >> 2, pi = rp & 3;
#pragma unroll
      for (int j = 0; j < 8; ++j) {
        int jj = (j + vrot) & 7;
        int hd = vsc + jj;
        unsigned val = (unsigned)ue.u[jj] | ((unsigned)uo.u[jj] << 16);
        *(unsigned*)&Vt[hd * 64 + ((pc ^ (hd & 7)) << 3) + pi * 2] = val;
      }
    }
    __syncthreads();

    tile_step(qfB, oaccB, mB, lB, qposB);  // heavy tile: every chunk
    if (c <= qbA)
      tile_step(qfA, oaccA, mA, lA, qposA);  // light tile: chunks 0..ib

    __syncthreads();
  }

  // epilogue: O^T -> O, 8B packed stores (4 consecutive hd per lane)
  float invA = 1.f / lA;
  float invB = 1.f / lB;
#pragma unroll
  for (int nt = 0; nt < 8; ++nt) {
    union { u16 u[4]; unsigned long long ll; } wA, wB;
    wA.u[0] = f2bf(oaccA[nt][0] * invA);
    wA.u[1] = f2bf(oaccA[nt][1] * invA);
    wA.u[2] = f2bf(oaccA[nt][2] * invA);
    wA.u[3] = f2bf(oaccA[nt][3] * invA);
    wB.u[0] = f2bf(oaccB[nt][0] * invB);
    wB.u[1] = f2bf(oaccB[nt][1] * invB);
    wB.u[2] = f2bf(oaccB[nt][2] * invB);
    wB.u[3] = f2bf(oaccB[nt][3] * invB);
    *(unsigned long long*)&O[(size_t)qposA * 4096 + h * 128 + nt * 16 + quad * 4] = wA.ll;
    *(unsigned long long*)&O[(size_t)qposB * 4096 + h * 128 + nt * 16 + quad * 4] = wB.ll;
  }
}

// ---------------------------------------------------------------------------
extern "C" void kernel_launch(void* const* d_in, const int* in_sizes, int n_in,
                              void* d_out, int out_size, void* d_ws, size_t ws_size,
                              hipStream_t stream) {
  const float* x  = (const float*)d_in[0];
  const float* fc = (const float*)d_in[1];
  const float* fs = (const float*)d_in[2];
  const float* wq = (const float*)d_in[3];
  const float* wk = (const float*)d_in[4];
  const float* wv = (const float*)d_in[5];
  const float* wo = (const float*)d_in[6];
  float* out = (float*)d_out;

  u16* q  = (u16*)d_ws;                      // 2048*4096
  u16* k  = q + (size_t)8388608;             // 2048*1024
  u16* v  = k + (size_t)2097152;
  u16* ao = v + (size_t)2097152;             // 2048*4096

  dim3 blk(256, 1, 1);
  const size_t NEED_FAST = 109051904ULL;     // bytes

  if (ws_size >= NEED_FAST) {
    u16* xb  = ao  + (size_t)8388608;        // 2048*4096
    u16* wqb = xb  + (size_t)8388608;        // 4096*4096
    u16* wkb = wqb + (size_t)16777216;       // 1024*4096
    u16* wvb = wkb + (size_t)4194304;        // 1024*4096
    u16* wob = wqb;                          // reuse after QKV GEMM

    hipLaunchKernelGGL(f2b_kernel, dim3(4096, 1, 1), blk, 0, stream, x,  xb,  1048576);
    hipLaunchKernelGGL(f2b_kernel, dim3(8192, 1, 1), blk, 0, stream, wq, wqb, 2097152);
    hipLaunchKernelGGL(f2b_kernel, dim3(2048, 1, 1), blk, 0, stream, wk, wkb, 524288);
    hipLaunchKernelGGL(f2b_kernel, dim3(2048, 1, 1), blk, 0, stream, wv, wvb, 524288);
    hipLaunchKernelGGL(gemm_qkv, dim3(48, 16, 1), blk, 0, stream, xb, wqb, wkb, wvb, q, k, v);
    hipLaunchKernelGGL(f2b_kernel, dim3(8192, 1, 1), blk, 0, stream, wo, wob, 2097152);
    hipLaunchKernelGGL(rope_kernel, dim3(20480, 1, 1), blk, 0, stream, q, k, fc, fs);
    hipLaunchKernelGGL(attn_kernel, dim3(16, 32, 1), blk, 0, stream, q, k, v, ao);
    hipLaunchKernelGGL(gemm_o, dim3(32, 16, 1), blk, 0, stream, ao, wob, out);
  } else {
    hipLaunchKernelGGL((gemm_bt<float, float, u16>), dim3(32, 16, 1), blk, 0, stream,
                       x, wq, q, 2048, 4096, 4096);
    hipLaunchKernelGGL((gemm_bt<float, float, u16>), dim3(8, 16, 1),  blk, 0, stream,
                       x, wk, k, 2048, 1024, 4096);
    hipLaunchKernelGGL((gemm_bt<float, float, u16>), dim3(8, 16, 1),  blk, 0, stream,
                       x, wv, v, 2048, 1024, 4096);
    hipLaunchKernelGGL(rope_kernel, dim3(20480, 1, 1), blk, 0, stream, q, k, fc, fs);
    hipLaunchKernelGGL(attn_kernel, dim3(16, 32, 1), blk, 0, stream, q, k, v, ao);
    hipLaunchKernelGGL((gemm_bt<u16, float, float>), dim3(32, 16, 1), blk, 0, stream,
                       ao, wo, out, 2048, 4096, 4096);
  }
}

// Round 2
// 554.194 us; speedup vs baseline: 1.4539x; 1.4539x over previous
//
#include <hip/hip_runtime.h>

typedef unsigned short u16;
typedef short bf16x8 __attribute__((ext_vector_type(8)));
typedef float f32x4 __attribute__((ext_vector_type(4)));

#define S_LEN 2048
#define ATT_SCALE 0.08838834764831845f
#define NEG_BIG  -1.0e30f

static __device__ __forceinline__ float bf2f(u16 u) {
  union { unsigned int i; float f; } v; v.i = ((unsigned int)u) << 16; return v.f;
}
static __device__ __forceinline__ u16 f2bf(float f) {
  union { float f; unsigned int i; } v; v.f = f;
  unsigned int x = v.i;
  return (u16)((x + 0x7fffu + ((x >> 16) & 1u)) >> 16);  // RNE
}

// async global->LDS, 16B per lane; lds dest = wave-uniform base + lane*16
static __device__ __forceinline__ void gl_lds16(const u16* g, u16* l) {
  __builtin_amdgcn_global_load_lds(
      (const __attribute__((address_space(1))) unsigned int*)g,
      (__attribute__((address_space(3))) unsigned int*)l, 16, 0, 0);
}

static __device__ __forceinline__ bf16x8 load8(const u16* p) { return *(const bf16x8*)p; }
static __device__ __forceinline__ bf16x8 load8(const float* p) {
  f32x4 a = *(const f32x4*)p;
  f32x4 b = *(const f32x4*)(p + 4);
  bf16x8 r;
  r[0] = (short)f2bf(a[0]); r[1] = (short)f2bf(a[1]);
  r[2] = (short)f2bf(a[2]); r[3] = (short)f2bf(a[3]);
  r[4] = (short)f2bf(b[0]); r[5] = (short)f2bf(b[1]);
  r[6] = (short)f2bf(b[2]); r[7] = (short)f2bf(b[3]);
  return r;
}
static __device__ __forceinline__ void store_out(u16* C, size_t i, float v)  { C[i] = f2bf(v); }
static __device__ __forceinline__ void store_out(float* C, size_t i, float v){ C[i] = v; }

// ---------------------------------------------------------------------------
// fp32 -> bf16 bulk convert (8 elems/thread)
// ---------------------------------------------------------------------------
__global__ __launch_bounds__(256) void f2b_kernel(
    const float* __restrict__ s, u16* __restrict__ d, int n8) {
  int i = blockIdx.x * 256 + threadIdx.x;
  if (i >= n8) return;
  *(bf16x8*)&d[(size_t)i * 8] = load8(s + (size_t)i * 8);
}

// ---------------------------------------------------------------------------
// m97-style bf16 GEMM core: C(M,N) = A(M,K)*B(N,K)^T.
// 128x128 tile, BK=64, global_load_lds width-16, XOR-swizzled unpadded LDS.
// ---------------------------------------------------------------------------
template <typename OT>
static __device__ __forceinline__ void gemm_core(
    const u16* __restrict__ A, const u16* __restrict__ B, OT* __restrict__ C,
    int K, int ldc, int bm, int bn) {
  __shared__ __align__(16) u16 As[128 * 64];
  __shared__ __align__(16) u16 Bs[128 * 64];
  const int tid  = threadIdx.x;
  const int lane = tid & 63;
  const int wave = tid >> 6;
  const int wm = (wave >> 1) << 6;
  const int wn = (wave & 1) << 6;
  const int col  = lane & 15;
  const int quad = lane >> 4;

  const f32x4 fzero = {0.f, 0.f, 0.f, 0.f};
  f32x4 acc[4][4];
#pragma unroll
  for (int i = 0; i < 4; ++i)
#pragma unroll
    for (int j = 0; j < 4; ++j) acc[i][j] = fzero;

  const int srow = (lane >> 3);
  const int sc8  = lane & 7;

  for (int k0 = 0; k0 < K; k0 += 64) {
#pragma unroll
    for (int i = 0; i < 4; ++i) {
      int r = wave * 32 + i * 8 + srow;
      int src = (sc8 ^ (r & 7)) << 3;
      gl_lds16(A + (size_t)(bm + r) * K + k0 + src, &As[(wave * 32 + i * 8) * 64]);
      gl_lds16(B + (size_t)(bn + r) * K + k0 + src, &Bs[(wave * 32 + i * 8) * 64]);
    }
    __syncthreads();
#pragma unroll
    for (int kk = 0; kk < 64; kk += 32) {
      bf16x8 af[4], bfr[4];
#pragma unroll
      for (int mt = 0; mt < 4; ++mt) {
        int row = wm + mt * 16 + col;
        af[mt] = *(const bf16x8*)&As[row * 64 + ((((kk >> 3) + quad) ^ (col & 7)) << 3)];
      }
#pragma unroll
      for (int nt = 0; nt < 4; ++nt) {
        int row = wn + nt * 16 + col;
        bfr[nt] = *(const bf16x8*)&Bs[row * 64 + ((((kk >> 3) + quad) ^ (col & 7)) << 3)];
      }
#pragma unroll
      for (int mt = 0; mt < 4; ++mt)
#pragma unroll
        for (int nt = 0; nt < 4; ++nt)
          acc[mt][nt] = __builtin_amdgcn_mfma_f32_16x16x32_bf16(
              af[mt], bfr[nt], acc[mt][nt], 0, 0, 0);
    }
    __syncthreads();
  }
#pragma unroll
  for (int mt = 0; mt < 4; ++mt)
#pragma unroll
    for (int nt = 0; nt < 4; ++nt)
#pragma unroll
      for (int r = 0; r < 4; ++r) {
        int row = bm + wm + mt * 16 + quad * 4 + r;
        int cn  = bn + wn + nt * 16 + col;
        store_out(C, (size_t)row * ldc + cn, acc[mt][nt][r]);
      }
}

__global__ __launch_bounds__(256) void gemm_qkv(
    const u16* __restrict__ xb, const u16* __restrict__ wqb,
    const u16* __restrict__ wkb, const u16* __restrict__ wvb,
    u16* __restrict__ q, u16* __restrict__ k, u16* __restrict__ v) {
  int bx = blockIdx.x;
  const u16* B; u16* C; int ldc, bn;
  if (bx < 32)      { B = wqb; C = q; ldc = 4096; bn = bx * 128; }
  else if (bx < 40) { B = wkb; C = k; ldc = 1024; bn = (bx - 32) * 128; }
  else              { B = wvb; C = v; ldc = 1024; bn = (bx - 40) * 128; }
  gemm_core<u16>(xb, B, C, 4096, ldc, blockIdx.y * 128, bn);
}

__global__ __launch_bounds__(256) void gemm_o(
    const u16* __restrict__ ao, const u16* __restrict__ wob, float* __restrict__ out) {
  gemm_core<float>(ao, wob, out, 4096, 4096, blockIdx.y * 128, blockIdx.x * 128);
}

// ---------------------------------------------------------------------------
// Fallback GEMM (fp32 staging convert, m93-class) for small workspace
// ---------------------------------------------------------------------------
#define LDK 72
template <typename AT, typename BT, typename OT>
__global__ __launch_bounds__(256) void gemm_bt(
    const AT* __restrict__ A, const BT* __restrict__ B,
    OT* __restrict__ C, int M, int N, int K) {
  __shared__ __align__(16) u16 As[128 * LDK];
  __shared__ __align__(16) u16 Bs[128 * LDK];
  const int tid  = threadIdx.x;
  const int lane = tid & 63;
  const int wave = tid >> 6;
  const int wm = (wave >> 1) << 6;
  const int wn = (wave & 1) << 6;
  const int col  = lane & 15;
  const int quad = lane >> 4;
  const int bm = blockIdx.y * 128;
  const int bn = blockIdx.x * 128;

  const f32x4 fzero = {0.f, 0.f, 0.f, 0.f};
  f32x4 acc[4][4];
#pragma unroll
  for (int i = 0; i < 4; ++i)
#pragma unroll
    for (int j = 0; j < 4; ++j) acc[i][j] = fzero;

  const int sr = tid >> 3;
  const int sc = (tid & 7) * 8;
  const AT* Aptr = A + (size_t)(bm + sr) * K + sc;
  const BT* Bptr = B + (size_t)(bn + sr) * K + sc;

  for (int k0 = 0; k0 < K; k0 += 64) {
#pragma unroll
    for (int p = 0; p < 4; ++p) {
      *(bf16x8*)&As[(sr + 32 * p) * LDK + sc] = load8(Aptr + (size_t)(32 * p) * K + k0);
      *(bf16x8*)&Bs[(sr + 32 * p) * LDK + sc] = load8(Bptr + (size_t)(32 * p) * K + k0);
    }
    __syncthreads();
#pragma unroll
    for (int kk = 0; kk < 64; kk += 32) {
      bf16x8 af[4], bfr[4];
#pragma unroll
      for (int mt = 0; mt < 4; ++mt)
        af[mt] = *(const bf16x8*)&As[(wm + mt * 16 + col) * LDK + kk + quad * 8];
#pragma unroll
      for (int nt = 0; nt < 4; ++nt)
        bfr[nt] = *(const bf16x8*)&Bs[(wn + nt * 16 + col) * LDK + kk + quad * 8];
#pragma unroll
      for (int mt = 0; mt < 4; ++mt)
#pragma unroll
        for (int nt = 0; nt < 4; ++nt)
          acc[mt][nt] = __builtin_amdgcn_mfma_f32_16x16x32_bf16(
              af[mt], bfr[nt], acc[mt][nt], 0, 0, 0);
    }
    __syncthreads();
  }
#pragma unroll
  for (int mt = 0; mt < 4; ++mt)
#pragma unroll
    for (int nt = 0; nt < 4; ++nt)
#pragma unroll
      for (int r = 0; r < 4; ++r) {
        int row = bm + wm + mt * 16 + quad * 4 + r;
        int cn  = bn + wn + nt * 16 + col;
        store_out(C, (size_t)row * N + cn, acc[mt][nt][r]);
      }
}

// ---------------------------------------------------------------------------
// RoPE in place on q (S,32,128) and k (S,8,128) bf16; scale folded into q.
// ---------------------------------------------------------------------------
__global__ __launch_bounds__(256) void rope_kernel(
    u16* __restrict__ q, u16* __restrict__ k,
    const float* __restrict__ cs, const float* __restrict__ sn) {
  int idx = blockIdx.x * 256 + threadIdx.x;
  const int QP = S_LEN * 32 * 64;
  u16* base;
  int s, i;
  bool isq = idx < QP;
  if (isq) {
    s = idx >> 11; int w = idx & 2047; i = w & 63;
    base = q + (size_t)s * 4096 + (w >> 6) * 128 + 2 * i;
  } else {
    int j = idx - QP;
    s = j >> 9; int w = j & 511; i = w & 63;
    base = k + (size_t)s * 1024 + (w >> 6) * 128 + 2 * i;
  }
  float c  = cs[s * 64 + i];
  float sv = sn[s * 64 + i];
  float x0 = bf2f(base[0]);
  float x1 = bf2f(base[1]);
  float r0 = x0 * c - x1 * sv;
  float r1 = x0 * sv + x1 * c;
  if (isq) { r0 *= ATT_SCALE; r1 *= ATT_SCALE; }
  base[0] = f2bf(r0);
  base[1] = f2bf(r1);
}

// ---------------------------------------------------------------------------
// Causal GQA flash attention, v5: paired q-tiles processed SEQUENTIALLY
// (single-tile register footprint, no spill) + double-buffered async staging.
// Block = q-tiles {ib, 31-ib}, one head; each block does exactly 33
// chunk-steps. Grid (16,32) = 512 blocks = 2 blocks/CU, perfectly balanced.
// Per round: issue next chunk's K global_load_lds + V global loads (regs),
// compute current chunk, then V unpack/ds_write, single barrier.
// ---------------------------------------------------------------------------
__global__ __launch_bounds__(256, 2) void attn_kernel(
    const u16* __restrict__ Q, const u16* __restrict__ K,
    const u16* __restrict__ V, u16* __restrict__ O) {
  const int ib   = blockIdx.x;       // 0..15
  const int h    = blockIdx.y;
  const int kvh  = h >> 2;
  const int tid  = threadIdx.x;
  const int lane = tid & 63;
  const int wave = tid >> 6;
  const int col  = lane & 15;
  const int quad = lane >> 4;

  __shared__ __align__(16) u16 Ks[2][64 * 128];  // [pos][hd], hd-chunks swizzled
  __shared__ __align__(16) u16 Vt[2][128 * 64];  // [hd][pos], pos-chunks swizzled

  const f32x4 fzero = {0.f, 0.f, 0.f, 0.f};

  // staging indices
  const int krow = lane >> 4;        // K: row within 4-row issue
  const int kcnk = lane & 15;        // K: chunk slot 0..15
  const int vsc  = (tid & 15) * 8;   // V: hd group base
  const int vrp  = tid >> 4;         // V: pos-pair 0..15 (block-wide)
  const int vrot = tid & 7;

  bf16x8 ve[2], vo[2];               // in-flight V rows (async-STAGE split)

  // issue-phase: K direct-to-LDS (async, vmcnt) + V global loads to regs
  auto stage_load = [&](int c, int buf) {
    const int pos0 = c * 64;
    u16* Kb = Ks[buf];
#pragma unroll
    for (int i = 0; i < 4; ++i) {
      int r = wave * 16 + i * 4 + krow;
      int src = ((kcnk & 8) | ((kcnk ^ r) & 7)) << 3;
      gl_lds16(&K[(size_t)(pos0 + r) * 1024 + kvh * 128 + src],
               &Kb[(wave * 16 + i * 4) * 128]);
    }
#pragma unroll
    for (int it = 0; it < 2; ++it) {
      int rp = vrp + it * 16;        // pos-pair 0..31
      const u16* vp = &V[(size_t)(pos0 + 2 * rp) * 1024 + kvh * 128 + vsc];
      ve[it] = *(const bf16x8*)vp;
      vo[it] = *(const bf16x8*)(vp + 1024);
    }
  };

  // write-phase: unpack V regs -> transposed, swizzled LDS
  auto stage_write = [&](int buf) {
    u16* Vb = Vt[buf];
#pragma unroll
    for (int it = 0; it < 2; ++it) {
      int rp = vrp + it * 16;
      union { bf16x8 v; u16 u[8]; } ue, uo;
      ue.v = ve[it]; uo.v = vo[it];
      int pc = rp >> 2, pi = rp & 3;
#pragma unroll
      for (int j = 0; j < 8; ++j) {
        int jj = (j + vrot) & 7;
        int hd = vsc + jj;
        unsigned val = (unsigned)ue.u[jj] | ((unsigned)uo.u[jj] << 16);
        *(unsigned*)&Vb[hd * 64 + ((pc ^ (hd & 7)) << 3) + pi * 2] = val;
      }
    }
  };

  for (int t = 0; t < 2; ++t) {
    const int qb   = t ? 31 - ib : ib;
    const int qpos = qb * 64 + wave * 16 + col;

    // Q fragments (B-operand: n=q=lane&15, k=quad*8+j), 4 d-windows
    bf16x8 qf[4];
#pragma unroll
    for (int kb = 0; kb < 4; ++kb)
      qf[kb] = *(const bf16x8*)&Q[(size_t)qpos * 4096 + h * 128 + kb * 32 + quad * 8];

    // O^T accumulator: oacc[nt][r] at hd = nt*16 + quad*4 + r, q = col
    f32x4 oacc[8];
#pragma unroll
    for (int nt = 0; nt < 8; ++nt) oacc[nt] = fzero;
    float m_ = NEG_BIG, l_ = 0.f;

    const int nchunk = qb + 1;
    int cur = 0;
    stage_load(0, 0);
    stage_write(0);
    __syncthreads();

    for (int c = 0; c < nchunk; ++c) {
      const int pos0 = c * 64;
      const bool pf = (c + 1 < nchunk);
      if (pf) stage_load(c + 1, cur ^ 1);   // overlaps with compute below

      const u16* Kb = Ks[cur];
      const u16* Vb = Vt[cur];

      // ---- S^T = K Q^T : 4 kpos-tiles (m) x 1 q-tile (n) per wave
      f32x4 sv[4];
#pragma unroll
      for (int kv = 0; kv < 4; ++kv) sv[kv] = fzero;
#pragma unroll
      for (int kv = 0; kv < 4; ++kv) {
        int r = kv * 16 + col;
#pragma unroll
        for (int kb = 0; kb < 4; ++kb) {
          int kq = kb * 4 + quad;
          int slot = (kq & 8) | ((kq ^ r) & 7);
          bf16x8 kf = *(const bf16x8*)&Kb[r * 128 + slot * 8];
          sv[kv] = __builtin_amdgcn_mfma_f32_16x16x32_bf16(kf, qf[kb], sv[kv], 0, 0, 0);
        }
      }

      // ---- softmax over this lane's 16 values (q = col fixed) + quad-reduce
      float mx = NEG_BIG;
#pragma unroll
      for (int kv = 0; kv < 4; ++kv)
#pragma unroll
        for (int r = 0; r < 4; ++r) {
          float s = (pos0 + kv * 16 + quad * 4 + r) <= qpos ? sv[kv][r] : NEG_BIG;
          sv[kv][r] = s;
          mx = fmaxf(mx, s);
        }
      mx = fmaxf(mx, __shfl_xor(mx, 16));
      mx = fmaxf(mx, __shfl_xor(mx, 32));
      float mnew  = fmaxf(m_, mx);
      float alpha = __expf(m_ - mnew);
      float ls = 0.f;
#pragma unroll
      for (int kv = 0; kv < 4; ++kv)
#pragma unroll
        for (int r = 0; r < 4; ++r) {
          float p = __expf(sv[kv][r] - mnew);
          sv[kv][r] = p;
          ls += p;
        }
      ls += __shfl_xor(ls, 16);
      ls += __shfl_xor(ls, 32);
      l_ = l_ * alpha + ls;
      m_ = mnew;
#pragma unroll
      for (int nt = 0; nt < 8; ++nt) {
        oacc[nt][0] *= alpha; oacc[nt][1] *= alpha;
        oacc[nt][2] *= alpha; oacc[nt][3] *= alpha;
      }

      // pack P^T tiles: pk[kv][hh] = bf16x2(p[2hh], p[2hh+1])
      unsigned pk[4][2];
#pragma unroll
      for (int kv = 0; kv < 4; ++kv) {
        pk[kv][0] = (unsigned)f2bf(sv[kv][0]) | ((unsigned)f2bf(sv[kv][1]) << 16);
        pk[kv][1] = (unsigned)f2bf(sv[kv][2]) | ((unsigned)f2bf(sv[kv][3]) << 16);
      }

      // ---- O^T += V^T P^T, P B-frags built by in-register shuffle transpose
      const int idxA = col + 16 * (2 * (quad & 1));
      const int idxB = idxA + 16;
      const bool hi  = quad >= 2;
#pragma unroll
      for (int kc = 0; kc < 2; ++kc) {
        unsigned a00 = __shfl(pk[2 * kc][0],     idxA);
        unsigned a01 = __shfl(pk[2 * kc][1],     idxA);
        unsigned a10 = __shfl(pk[2 * kc + 1][0], idxA);
        unsigned a11 = __shfl(pk[2 * kc + 1][1], idxA);
        unsigned b00 = __shfl(pk[2 * kc][0],     idxB);
        unsigned b01 = __shfl(pk[2 * kc][1],     idxB);
        unsigned b10 = __shfl(pk[2 * kc + 1][0], idxB);
        unsigned b11 = __shfl(pk[2 * kc + 1][1], idxB);
        union { unsigned u[4]; bf16x8 v; } pb;
        pb.u[0] = hi ? a10 : a00;
        pb.u[1] = hi ? a11 : a01;
        pb.u[2] = hi ? b10 : b00;
        pb.u[3] = hi ? b11 : b01;
#pragma unroll
        for (int nt = 0; nt < 8; ++nt) {
          int hd = nt * 16 + col;
          int pc = kc * 4 + quad;
          bf16x8 vf = *(const bf16x8*)&Vb[hd * 64 + ((pc ^ (hd & 7)) << 3)];
          oacc[nt] = __builtin_amdgcn_mfma_f32_16x16x32_bf16(vf, pb.v, oacc[nt], 0, 0, 0);
        }
      }

      if (pf) stage_write(cur ^ 1);   // vmcnt wait lands after compute
      __syncthreads();
      cur ^= 1;
    }

    // epilogue: O^T -> O, 8B packed stores (4 consecutive hd per lane)
    float inv = 1.f / l_;
#pragma unroll
    for (int nt = 0; nt < 8; ++nt) {
      union { u16 u[4]; unsigned long long ll; } w;
      w.u[0] = f2bf(oacc[nt][0] * inv);
      w.u[1] = f2bf(oacc[nt][1] * inv);
      w.u[2] = f2bf(oacc[nt][2] * inv);
      w.u[3] = f2bf(oacc[nt][3] * inv);
      *(unsigned long long*)&O[(size_t)qpos * 4096 + h * 128 + nt * 16 + quad * 4] = w.ll;
    }
  }
}

// ---------------------------------------------------------------------------
extern "C" void kernel_launch(void* const* d_in, const int* in_sizes, int n_in,
                              void* d_out, int out_size, void* d_ws, size_t ws_size,
                              hipStream_t stream) {
  const float* x  = (const float*)d_in[0];
  const float* fc = (const float*)d_in[1];
  const float* fs = (const float*)d_in[2];
  const float* wq = (const float*)d_in[3];
  const float* wk = (const float*)d_in[4];
  const float* wv = (const float*)d_in[5];
  const float* wo = (const float*)d_in[6];
  float* out = (float*)d_out;

  u16* q  = (u16*)d_ws;                      // 2048*4096
  u16* k  = q + (size_t)8388608;             // 2048*1024
  u16* v  = k + (size_t)2097152;
  u16* ao = v + (size_t)2097152;             // 2048*4096

  dim3 blk(256, 1, 1);
  const size_t NEED_FAST = 109051904ULL;     // bytes

  if (ws_size >= NEED_FAST) {
    u16* xb  = ao  + (size_t)8388608;        // 2048*4096
    u16* wqb = xb  + (size_t)8388608;        // 4096*4096
    u16* wkb = wqb + (size_t)16777216;       // 1024*4096
    u16* wvb = wkb + (size_t)4194304;        // 1024*4096
    u16* wob = wqb;                          // reuse after QKV GEMM

    hipLaunchKernelGGL(f2b_kernel, dim3(4096, 1, 1), blk, 0, stream, x,  xb,  1048576);
    hipLaunchKernelGGL(f2b_kernel, dim3(8192, 1, 1), blk, 0, stream, wq, wqb, 2097152);
    hipLaunchKernelGGL(f2b_kernel, dim3(2048, 1, 1), blk, 0, stream, wk, wkb, 524288);
    hipLaunchKernelGGL(f2b_kernel, dim3(2048, 1, 1), blk, 0, stream, wv, wvb, 524288);
    hipLaunchKernelGGL(gemm_qkv, dim3(48, 16, 1), blk, 0, stream, xb, wqb, wkb, wvb, q, k, v);
    hipLaunchKernelGGL(f2b_kernel, dim3(8192, 1, 1), blk, 0, stream, wo, wob, 2097152);
    hipLaunchKernelGGL(rope_kernel, dim3(20480, 1, 1), blk, 0, stream, q, k, fc, fs);
    hipLaunchKernelGGL(attn_kernel, dim3(16, 32, 1), blk, 0, stream, q, k, v, ao);
    hipLaunchKernelGGL(gemm_o, dim3(32, 16, 1), blk, 0, stream, ao, wob, out);
  } else {
    hipLaunchKernelGGL((gemm_bt<float, float, u16>), dim3(32, 16, 1), blk, 0, stream,
                       x, wq, q, 2048, 4096, 4096);
    hipLaunchKernelGGL((gemm_bt<float, float, u16>), dim3(8, 16, 1),  blk, 0, stream,
                       x, wk, k, 2048, 1024, 4096);
    hipLaunchKernelGGL((gemm_bt<float, float, u16>), dim3(8, 16, 1),  blk, 0, stream,
                       x, wv, v, 2048, 1024, 4096);
    hipLaunchKernelGGL(rope_kernel, dim3(20480, 1, 1), blk, 0, stream, q, k, fc, fs);
    hipLaunchKernelGGL(attn_kernel, dim3(16, 32, 1), blk, 0, stream, q, k, v, ao);
    hipLaunchKernelGGL((gemm_bt<u16, float, float>), dim3(32, 16, 1), blk, 0, stream,
                       ao, wo, out, 2048, 4096, 4096);
  }
}

// Round 3
// 542.406 us; speedup vs baseline: 1.4855x; 1.0217x over previous
//
#include <hip/hip_runtime.h>

typedef unsigned short u16;
typedef short bf16x8 __attribute__((ext_vector_type(8)));
typedef float f32x4 __attribute__((ext_vector_type(4)));

#define S_LEN 2048
// log2(e) folded into the q scale => softmax runs in exp2 domain
#define ATT_SCALE (0.08838834764831845f * 1.4426950408889634f)
#define NEG_BIG  -1.0e30f

static __device__ __forceinline__ float bf2f(u16 u) {
  union { unsigned int i; float f; } v; v.i = ((unsigned int)u) << 16; return v.f;
}
static __device__ __forceinline__ u16 f2bf(float f) {
  union { float f; unsigned int i; } v; v.f = f;
  unsigned int x = v.i;
  return (u16)((x + 0x7fffu + ((x >> 16) & 1u)) >> 16);  // RNE
}
static __device__ __forceinline__ float fexp2(float x) {
  return __builtin_amdgcn_exp2f(x);
}

// async global->LDS, 16B per lane; lds dest = wave-uniform base + lane*16
static __device__ __forceinline__ void gl_lds16(const u16* g, u16* l) {
  __builtin_amdgcn_global_load_lds(
      (const __attribute__((address_space(1))) unsigned int*)g,
      (__attribute__((address_space(3))) unsigned int*)l, 16, 0, 0);
}

static __device__ __forceinline__ bf16x8 load8(const u16* p) { return *(const bf16x8*)p; }
static __device__ __forceinline__ bf16x8 load8(const float* p) {
  f32x4 a = *(const f32x4*)p;
  f32x4 b = *(const f32x4*)(p + 4);
  bf16x8 r;
  r[0] = (short)f2bf(a[0]); r[1] = (short)f2bf(a[1]);
  r[2] = (short)f2bf(a[2]); r[3] = (short)f2bf(a[3]);
  r[4] = (short)f2bf(b[0]); r[5] = (short)f2bf(b[1]);
  r[6] = (short)f2bf(b[2]); r[7] = (short)f2bf(b[3]);
  return r;
}
static __device__ __forceinline__ void store_out(u16* C, size_t i, float v)  { C[i] = f2bf(v); }
static __device__ __forceinline__ void store_out(float* C, size_t i, float v){ C[i] = v; }

// ---------------------------------------------------------------------------
// fp32 -> bf16 bulk convert (8 elems/thread)
// ---------------------------------------------------------------------------
__global__ __launch_bounds__(256) void f2b_kernel(
    const float* __restrict__ s, u16* __restrict__ d, int n8) {
  int i = blockIdx.x * 256 + threadIdx.x;
  if (i >= n8) return;
  *(bf16x8*)&d[(size_t)i * 8] = load8(s + (size_t)i * 8);
}

// ---------------------------------------------------------------------------
// m97-style bf16 GEMM core: C(M,N) = A(M,K)*B(N,K)^T.
// 128x128 tile, BK=64, global_load_lds width-16, XOR-swizzled unpadded LDS.
// ---------------------------------------------------------------------------
template <typename OT>
static __device__ __forceinline__ void gemm_core(
    const u16* __restrict__ A, const u16* __restrict__ B, OT* __restrict__ C,
    int K, int ldc, int bm, int bn) {
  __shared__ __align__(16) u16 As[128 * 64];
  __shared__ __align__(16) u16 Bs[128 * 64];
  const int tid  = threadIdx.x;
  const int lane = tid & 63;
  const int wave = tid >> 6;
  const int wm = (wave >> 1) << 6;
  const int wn = (wave & 1) << 6;
  const int col  = lane & 15;
  const int quad = lane >> 4;

  const f32x4 fzero = {0.f, 0.f, 0.f, 0.f};
  f32x4 acc[4][4];
#pragma unroll
  for (int i = 0; i < 4; ++i)
#pragma unroll
    for (int j = 0; j < 4; ++j) acc[i][j] = fzero;

  const int srow = (lane >> 3);
  const int sc8  = lane & 7;

  for (int k0 = 0; k0 < K; k0 += 64) {
#pragma unroll
    for (int i = 0; i < 4; ++i) {
      int r = wave * 32 + i * 8 + srow;
      int src = (sc8 ^ (r & 7)) << 3;
      gl_lds16(A + (size_t)(bm + r) * K + k0 + src, &As[(wave * 32 + i * 8) * 64]);
      gl_lds16(B + (size_t)(bn + r) * K + k0 + src, &Bs[(wave * 32 + i * 8) * 64]);
    }
    __syncthreads();
#pragma unroll
    for (int kk = 0; kk < 64; kk += 32) {
      bf16x8 af[4], bfr[4];
#pragma unroll
      for (int mt = 0; mt < 4; ++mt) {
        int row = wm + mt * 16 + col;
        af[mt] = *(const bf16x8*)&As[row * 64 + ((((kk >> 3) + quad) ^ (col & 7)) << 3)];
      }
#pragma unroll
      for (int nt = 0; nt < 4; ++nt) {
        int row = wn + nt * 16 + col;
        bfr[nt] = *(const bf16x8*)&Bs[row * 64 + ((((kk >> 3) + quad) ^ (col & 7)) << 3)];
      }
#pragma unroll
      for (int mt = 0; mt < 4; ++mt)
#pragma unroll
        for (int nt = 0; nt < 4; ++nt)
          acc[mt][nt] = __builtin_amdgcn_mfma_f32_16x16x32_bf16(
              af[mt], bfr[nt], acc[mt][nt], 0, 0, 0);
    }
    __syncthreads();
  }
#pragma unroll
  for (int mt = 0; mt < 4; ++mt)
#pragma unroll
    for (int nt = 0; nt < 4; ++nt)
#pragma unroll
      for (int r = 0; r < 4; ++r) {
        int row = bm + wm + mt * 16 + quad * 4 + r;
        int cn  = bn + wn + nt * 16 + col;
        store_out(C, (size_t)row * ldc + cn, acc[mt][nt][r]);
      }
}

__global__ __launch_bounds__(256) void gemm_qkv(
    const u16* __restrict__ xb, const u16* __restrict__ wqb,
    const u16* __restrict__ wkb, const u16* __restrict__ wvb,
    u16* __restrict__ q, u16* __restrict__ k, u16* __restrict__ v) {
  int bx = blockIdx.x;
  const u16* B; u16* C; int ldc, bn;
  if (bx < 32)      { B = wqb; C = q; ldc = 4096; bn = bx * 128; }
  else if (bx < 40) { B = wkb; C = k; ldc = 1024; bn = (bx - 32) * 128; }
  else              { B = wvb; C = v; ldc = 1024; bn = (bx - 40) * 128; }
  gemm_core<u16>(xb, B, C, 4096, ldc, blockIdx.y * 128, bn);
}

__global__ __launch_bounds__(256) void gemm_o(
    const u16* __restrict__ ao, const u16* __restrict__ wob, float* __restrict__ out) {
  gemm_core<float>(ao, wob, out, 4096, 4096, blockIdx.y * 128, blockIdx.x * 128);
}

// ---------------------------------------------------------------------------
// Fallback GEMM (fp32 staging convert, m93-class) for small workspace
// ---------------------------------------------------------------------------
#define LDK 72
template <typename AT, typename BT, typename OT>
__global__ __launch_bounds__(256) void gemm_bt(
    const AT* __restrict__ A, const BT* __restrict__ B,
    OT* __restrict__ C, int M, int N, int K) {
  __shared__ __align__(16) u16 As[128 * LDK];
  __shared__ __align__(16) u16 Bs[128 * LDK];
  const int tid  = threadIdx.x;
  const int lane = tid & 63;
  const int wave = tid >> 6;
  const int wm = (wave >> 1) << 6;
  const int wn = (wave & 1) << 6;
  const int col  = lane & 15;
  const int quad = lane >> 4;
  const int bm = blockIdx.y * 128;
  const int bn = blockIdx.x * 128;

  const f32x4 fzero = {0.f, 0.f, 0.f, 0.f};
  f32x4 acc[4][4];
#pragma unroll
  for (int i = 0; i < 4; ++i)
#pragma unroll
    for (int j = 0; j < 4; ++j) acc[i][j] = fzero;

  const int sr = tid >> 3;
  const int sc = (tid & 7) * 8;
  const AT* Aptr = A + (size_t)(bm + sr) * K + sc;
  const BT* Bptr = B + (size_t)(bn + sr) * K + sc;

  for (int k0 = 0; k0 < K; k0 += 64) {
#pragma unroll
    for (int p = 0; p < 4; ++p) {
      *(bf16x8*)&As[(sr + 32 * p) * LDK + sc] = load8(Aptr + (size_t)(32 * p) * K + k0);
      *(bf16x8*)&Bs[(sr + 32 * p) * LDK + sc] = load8(Bptr + (size_t)(32 * p) * K + k0);
    }
    __syncthreads();
#pragma unroll
    for (int kk = 0; kk < 64; kk += 32) {
      bf16x8 af[4], bfr[4];
#pragma unroll
      for (int mt = 0; mt < 4; ++mt)
        af[mt] = *(const bf16x8*)&As[(wm + mt * 16 + col) * LDK + kk + quad * 8];
#pragma unroll
      for (int nt = 0; nt < 4; ++nt)
        bfr[nt] = *(const bf16x8*)&Bs[(wn + nt * 16 + col) * LDK + kk + quad * 8];
#pragma unroll
      for (int mt = 0; mt < 4; ++mt)
#pragma unroll
        for (int nt = 0; nt < 4; ++nt)
          acc[mt][nt] = __builtin_amdgcn_mfma_f32_16x16x32_bf16(
              af[mt], bfr[nt], acc[mt][nt], 0, 0, 0);
    }
    __syncthreads();
  }
#pragma unroll
  for (int mt = 0; mt < 4; ++mt)
#pragma unroll
    for (int nt = 0; nt < 4; ++nt)
#pragma unroll
      for (int r = 0; r < 4; ++r) {
        int row = bm + wm + mt * 16 + quad * 4 + r;
        int cn  = bn + wn + nt * 16 + col;
        store_out(C, (size_t)row * N + cn, acc[mt][nt][r]);
      }
}

// ---------------------------------------------------------------------------
// RoPE in place on q (S,32,128) and k (S,8,128) bf16; scale folded into q.
// ---------------------------------------------------------------------------
__global__ __launch_bounds__(256) void rope_kernel(
    u16* __restrict__ q, u16* __restrict__ k,
    const float* __restrict__ cs, const float* __restrict__ sn) {
  int idx = blockIdx.x * 256 + threadIdx.x;
  const int QP = S_LEN * 32 * 64;
  u16* base;
  int s, i;
  bool isq = idx < QP;
  if (isq) {
    s = idx >> 11; int w = idx & 2047; i = w & 63;
    base = q + (size_t)s * 4096 + (w >> 6) * 128 + 2 * i;
  } else {
    int j = idx - QP;
    s = j >> 9; int w = j & 511; i = w & 63;
    base = k + (size_t)s * 1024 + (w >> 6) * 128 + 2 * i;
  }
  float c  = cs[s * 64 + i];
  float sv = sn[s * 64 + i];
  float x0 = bf2f(base[0]);
  float x1 = bf2f(base[1]);
  float r0 = x0 * c - x1 * sv;
  float r1 = x0 * sv + x1 * c;
  if (isq) { r0 *= ATT_SCALE; r1 *= ATT_SCALE; }
  base[0] = f2bf(r0);
  base[1] = f2bf(r1);
}

// ---------------------------------------------------------------------------
// Causal GQA flash attention, v6: 8-wave blocks with intra-block split-K.
// Block = q-tiles {ib, 31-ib} processed sequentially; within each tile the
// chunk range is split between wave-group 0 (waves 0-3) and group 1 (waves
// 4-7), each with private K/V LDS buffers; (m,l,O) merged via LDS at pass
// end. Rounds/block = 17 for EVERY block (balanced). Grid (16,32) = 512
// blocks x 8 waves = 16 waves/CU (4/SIMD) -> 2x occupancy vs v5.
// Softmax in exp2 domain (log2e folded into RoPE q-scale); defer-max (T13);
// setprio around MFMA clusters (T5); diagonal-only masking.
// ---------------------------------------------------------------------------
__global__ __launch_bounds__(512, 4) void attn_kernel(
    const u16* __restrict__ Q, const u16* __restrict__ K,
    const u16* __restrict__ V, u16* __restrict__ O) {
  const int ib   = blockIdx.x;       // 0..15
  const int h    = blockIdx.y;
  const int kvh  = h >> 2;
  const int tid  = threadIdx.x;
  const int lane = tid & 63;
  const int wave = tid >> 6;         // 0..7
  const int grp  = wave >> 2;        // 0..1
  const int wl   = wave & 3;         // wave within group
  const int col  = lane & 15;
  const int quad = lane >> 4;
  const int gt   = tid & 255;        // thread within group

  // per-group: K chunk [64 pos][128 hd] (8192 u16) + V^T [128 hd][64 pos]
  __shared__ __align__(16) u16 SMEM[2][16384];
  u16* Kb = &SMEM[grp][0];
  u16* Vb = &SMEM[grp][8192];

  const f32x4 fzero = {0.f, 0.f, 0.f, 0.f};

  // staging indices
  const int krow = lane >> 4;        // K: row within 4-row issue
  const int kcnk = lane & 15;        // K: chunk slot 0..15
  const int vsc  = (gt & 15) * 8;    // V: hd group base
  const int vrp  = gt >> 4;          // V: pos-pair 0..15 (group-wide)
  const int vrot = gt & 7;

  for (int t = 0; t < 2; ++t) {
    const int qb   = t ? 31 - ib : ib;
    const int qpos = qb * 64 + wl * 16 + col;
    const int ql   = wl * 16 + col;  // q-row within tile

    // Q fragments (B-operand: n=q=lane&15, k=quad*8+j), 4 d-windows
    bf16x8 qf[4];
#pragma unroll
    for (int kb = 0; kb < 4; ++kb)
      qf[kb] = *(const bf16x8*)&Q[(size_t)qpos * 4096 + h * 128 + kb * 32 + quad * 8];

    // O^T accumulator: oacc[nt][r] at hd = nt*16 + quad*4 + r, q = col
    f32x4 oacc[8];
#pragma unroll
    for (int nt = 0; nt < 8; ++nt) oacc[nt] = fzero;
    float m_ = NEG_BIG, l_ = 0.f;

    const int n  = qb + 1;           // total chunks for this tile
    const int h0 = (n + 1) >> 1;     // group0 count (>= group1 count)
    const int c0 = grp ? h0 : 0;
    const int c1 = grp ? n  : h0;

    for (int rnd = 0; rnd < h0; ++rnd) {
      const int c = c0 + rnd;
      const bool act = c < c1;       // group-uniform
      if (act) {
        const int pos0 = c * 64;
        // ---- stage K via global_load_lds: wave stages rows wl*16..+15
#pragma unroll
        for (int i = 0; i < 4; ++i) {
          int r = wl * 16 + i * 4 + krow;
          int src = ((kcnk & 8) | ((kcnk ^ r) & 7)) << 3;
          gl_lds16(&K[(size_t)(pos0 + r) * 1024 + kvh * 128 + src],
                   &Kb[(wl * 16 + i * 4) * 128]);
        }
        // ---- stage V^T: packed pos-pair b32 writes, swizzled pos-chunks
#pragma unroll
        for (int it = 0; it < 2; ++it) {
          int rp = vrp + it * 16;    // pos-pair 0..31
          const u16* vp = &V[(size_t)(pos0 + 2 * rp) * 1024 + kvh * 128 + vsc];
          union { bf16x8 v; u16 u[8]; } ue, uo;
          ue.v = *(const bf16x8*)vp;
          uo.v = *(const bf16x8*)(vp + 1024);
          int pc = rp >> 2, pi = rp & 3;
#pragma unroll
          for (int j = 0; j < 8; ++j) {
            int jj = (j + vrot) & 7;
            int hd = vsc + jj;
            unsigned val = (unsigned)ue.u[jj] | ((unsigned)uo.u[jj] << 16);
            *(unsigned*)&Vb[hd * 64 + ((pc ^ (hd & 7)) << 3) + pi * 2] = val;
          }
        }
      }
      __syncthreads();
      if (act) {
        const int pos0 = c * 64;
        const bool diag = (c == qb);

        // ---- S^T = K Q^T : 4 kpos-tiles (m) x 1 q-tile (n) per wave
        f32x4 sv[4];
#pragma unroll
        for (int kv = 0; kv < 4; ++kv) sv[kv] = fzero;
        __builtin_amdgcn_s_setprio(1);
#pragma unroll
        for (int kv = 0; kv < 4; ++kv) {
          int r = kv * 16 + col;
#pragma unroll
          for (int kb = 0; kb < 4; ++kb) {
            int kq = kb * 4 + quad;
            int slot = (kq & 8) | ((kq ^ r) & 7);
            bf16x8 kf = *(const bf16x8*)&Kb[r * 128 + slot * 8];
            sv[kv] = __builtin_amdgcn_mfma_f32_16x16x32_bf16(kf, qf[kb], sv[kv], 0, 0, 0);
          }
        }
        __builtin_amdgcn_s_setprio(0);

        // ---- softmax (exp2 domain) over lane's 16 values + quad-reduce
        float mx = NEG_BIG;
        if (diag) {
#pragma unroll
          for (int kv = 0; kv < 4; ++kv)
#pragma unroll
            for (int r = 0; r < 4; ++r) {
              float s = (pos0 + kv * 16 + quad * 4 + r) <= qpos ? sv[kv][r] : NEG_BIG;
              sv[kv][r] = s;
              mx = fmaxf(mx, s);
            }
        } else {
#pragma unroll
          for (int kv = 0; kv < 4; ++kv)
#pragma unroll
            for (int r = 0; r < 4; ++r) mx = fmaxf(mx, sv[kv][r]);
        }
        mx = fmaxf(mx, __shfl_xor(mx, 16));
        mx = fmaxf(mx, __shfl_xor(mx, 32));
        // defer-max: skip rescale while chunk max within 8 (2^8 headroom)
        if (!__all(mx - m_ <= 8.f)) {
          float mnew  = fmaxf(m_, mx);
          float alpha = fexp2(m_ - mnew);
          l_ *= alpha;
#pragma unroll
          for (int nt = 0; nt < 8; ++nt) {
            oacc[nt][0] *= alpha; oacc[nt][1] *= alpha;
            oacc[nt][2] *= alpha; oacc[nt][3] *= alpha;
          }
          m_ = mnew;
        }
        float ls = 0.f;
#pragma unroll
        for (int kv = 0; kv < 4; ++kv)
#pragma unroll
          for (int r = 0; r < 4; ++r) {
            float p = fexp2(sv[kv][r] - m_);
            sv[kv][r] = p;
            ls += p;
          }
        ls += __shfl_xor(ls, 16);
        ls += __shfl_xor(ls, 32);
        l_ += ls;

        // pack P^T tiles: pk[kv][hh] = bf16x2(p[2hh], p[2hh+1])
        unsigned pk[4][2];
#pragma unroll
        for (int kv = 0; kv < 4; ++kv) {
          pk[kv][0] = (unsigned)f2bf(sv[kv][0]) | ((unsigned)f2bf(sv[kv][1]) << 16);
          pk[kv][1] = (unsigned)f2bf(sv[kv][2]) | ((unsigned)f2bf(sv[kv][3]) << 16);
        }

        // ---- O^T += V^T P^T, P B-frags built by in-register shuffles
        const int idxA = col + 16 * (2 * (quad & 1));
        const int idxB = idxA + 16;
        const bool hi  = quad >= 2;
#pragma unroll
        for (int kc = 0; kc < 2; ++kc) {
          unsigned a00 = __shfl(pk[2 * kc][0],     idxA);
          unsigned a01 = __shfl(pk[2 * kc][1],     idxA);
          unsigned a10 = __shfl(pk[2 * kc + 1][0], idxA);
          unsigned a11 = __shfl(pk[2 * kc + 1][1], idxA);
          unsigned b00 = __shfl(pk[2 * kc][0],     idxB);
          unsigned b01 = __shfl(pk[2 * kc][1],     idxB);
          unsigned b10 = __shfl(pk[2 * kc + 1][0], idxB);
          unsigned b11 = __shfl(pk[2 * kc + 1][1], idxB);
          union { unsigned u[4]; bf16x8 v; } pb;
          pb.u[0] = hi ? a10 : a00;
          pb.u[1] = hi ? a11 : a01;
          pb.u[2] = hi ? b10 : b00;
          pb.u[3] = hi ? b11 : b01;
          __builtin_amdgcn_s_setprio(1);
#pragma unroll
          for (int nt = 0; nt < 8; ++nt) {
            int hd = nt * 16 + col;
            int pc = kc * 4 + quad;
            bf16x8 vf = *(const bf16x8*)&Vb[hd * 64 + ((pc ^ (hd & 7)) << 3)];
            oacc[nt] = __builtin_amdgcn_mfma_f32_16x16x32_bf16(vf, pb.v, oacc[nt], 0, 0, 0);
          }
          __builtin_amdgcn_s_setprio(0);
        }
      }
      __syncthreads();
    }

    // ---- cross-group merge via LDS (reuses staging space), then store
    float* MF = (float*)&SMEM[0][0];       // [64 q][132 hd-padded] f32
    float* ML = MF + 64 * 132;             // m,l per q
    if (grp == 1) {
#pragma unroll
      for (int nt = 0; nt < 8; ++nt)
        *(f32x4*)&MF[ql * 132 + nt * 16 + quad * 4] = oacc[nt];
      if (quad == 0) { ML[2 * ql] = m_; ML[2 * ql + 1] = l_; }
    }
    __syncthreads();
    if (grp == 0) {
      float m1 = ML[2 * ql], l1 = ML[2 * ql + 1];
      float mn = fmaxf(m_, m1);
      float a0 = fexp2(m_ - mn), a1 = fexp2(m1 - mn);
      float li = 1.f / (l_ * a0 + l1 * a1);
      a0 *= li; a1 *= li;
#pragma unroll
      for (int nt = 0; nt < 8; ++nt) {
        f32x4 o1 = *(const f32x4*)&MF[ql * 132 + nt * 16 + quad * 4];
        union { u16 u[4]; unsigned long long ll; } w;
        w.u[0] = f2bf(oacc[nt][0] * a0 + o1[0] * a1);
        w.u[1] = f2bf(oacc[nt][1] * a0 + o1[1] * a1);
        w.u[2] = f2bf(oacc[nt][2] * a0 + o1[2] * a1);
        w.u[3] = f2bf(oacc[nt][3] * a0 + o1[3] * a1);
        *(unsigned long long*)&O[(size_t)qpos * 4096 + h * 128 + nt * 16 + quad * 4] = w.ll;
      }
    }
    __syncthreads();
  }
}

// ---------------------------------------------------------------------------
extern "C" void kernel_launch(void* const* d_in, const int* in_sizes, int n_in,
                              void* d_out, int out_size, void* d_ws, size_t ws_size,
                              hipStream_t stream) {
  const float* x  = (const float*)d_in[0];
  const float* fc = (const float*)d_in[1];
  const float* fs = (const float*)d_in[2];
  const float* wq = (const float*)d_in[3];
  const float* wk = (const float*)d_in[4];
  const float* wv = (const float*)d_in[5];
  const float* wo = (const float*)d_in[6];
  float* out = (float*)d_out;

  u16* q  = (u16*)d_ws;                      // 2048*4096
  u16* k  = q + (size_t)8388608;             // 2048*1024
  u16* v  = k + (size_t)2097152;
  u16* ao = v + (size_t)2097152;             // 2048*4096

  dim3 blk(256, 1, 1);
  dim3 ablk(512, 1, 1);
  const size_t NEED_FAST = 109051904ULL;     // bytes

  if (ws_size >= NEED_FAST) {
    u16* xb  = ao  + (size_t)8388608;        // 2048*4096
    u16* wqb = xb  + (size_t)8388608;        // 4096*4096
    u16* wkb = wqb + (size_t)16777216;       // 1024*4096
    u16* wvb = wkb + (size_t)4194304;        // 1024*4096
    u16* wob = wqb;                          // reuse after QKV GEMM

    hipLaunchKernelGGL(f2b_kernel, dim3(4096, 1, 1), blk, 0, stream, x,  xb,  1048576);
    hipLaunchKernelGGL(f2b_kernel, dim3(8192, 1, 1), blk, 0, stream, wq, wqb, 2097152);
    hipLaunchKernelGGL(f2b_kernel, dim3(2048, 1, 1), blk, 0, stream, wk, wkb, 524288);
    hipLaunchKernelGGL(f2b_kernel, dim3(2048, 1, 1), blk, 0, stream, wv, wvb, 524288);
    hipLaunchKernelGGL(gemm_qkv, dim3(48, 16, 1), blk, 0, stream, xb, wqb, wkb, wvb, q, k, v);
    hipLaunchKernelGGL(f2b_kernel, dim3(8192, 1, 1), blk, 0, stream, wo, wob, 2097152);
    hipLaunchKernelGGL(rope_kernel, dim3(20480, 1, 1), blk, 0, stream, q, k, fc, fs);
    hipLaunchKernelGGL(attn_kernel, dim3(16, 32, 1), ablk, 0, stream, q, k, v, ao);
    hipLaunchKernelGGL(gemm_o, dim3(32, 16, 1), blk, 0, stream, ao, wob, out);
  } else {
    hipLaunchKernelGGL((gemm_bt<float, float, u16>), dim3(32, 16, 1), blk, 0, stream,
                       x, wq, q, 2048, 4096, 4096);
    hipLaunchKernelGGL((gemm_bt<float, float, u16>), dim3(8, 16, 1),  blk, 0, stream,
                       x, wk, k, 2048, 1024, 4096);
    hipLaunchKernelGGL((gemm_bt<float, float, u16>), dim3(8, 16, 1),  blk, 0, stream,
                       x, wv, v, 2048, 1024, 4096);
    hipLaunchKernelGGL(rope_kernel, dim3(20480, 1, 1), blk, 0, stream, q, k, fc, fs);
    hipLaunchKernelGGL(attn_kernel, dim3(16, 32, 1), ablk, 0, stream, q, k, v, ao);
    hipLaunchKernelGGL((gemm_bt<u16, float, float>), dim3(32, 16, 1), blk, 0, stream,
                       ao, wo, out, 2048, 4096, 4096);
  }
}

// Round 4
// 537.515 us; speedup vs baseline: 1.4991x; 1.0091x over previous
//
#include <hip/hip_runtime.h>

typedef unsigned short u16;
typedef short bf16x8 __attribute__((ext_vector_type(8)));
typedef float f32x4 __attribute__((ext_vector_type(4)));

#define S_LEN 2048
// log2(e) folded into the q scale => softmax runs in exp2 domain
#define ATT_SCALE (0.08838834764831845f * 1.4426950408889634f)
#define NEG_BIG  -1.0e30f

static __device__ __forceinline__ float bf2f(u16 u) {
  union { unsigned int i; float f; } v; v.i = ((unsigned int)u) << 16; return v.f;
}
static __device__ __forceinline__ u16 f2bf(float f) {
  union { float f; unsigned int i; } v; v.f = f;
  unsigned int x = v.i;
  return (u16)((x + 0x7fffu + ((x >> 16) & 1u)) >> 16);  // RNE
}
static __device__ __forceinline__ float fexp2(float x) {
  return __builtin_amdgcn_exp2f(x);
}

// async global->LDS, 16B per lane; lds dest = wave-uniform base + lane*16
static __device__ __forceinline__ void gl_lds16(const u16* g, u16* l) {
  __builtin_amdgcn_global_load_lds(
      (const __attribute__((address_space(1))) unsigned int*)g,
      (__attribute__((address_space(3))) unsigned int*)l, 16, 0, 0);
}

static __device__ __forceinline__ bf16x8 load8(const u16* p) { return *(const bf16x8*)p; }
static __device__ __forceinline__ bf16x8 load8(const float* p) {
  f32x4 a = *(const f32x4*)p;
  f32x4 b = *(const f32x4*)(p + 4);
  bf16x8 r;
  r[0] = (short)f2bf(a[0]); r[1] = (short)f2bf(a[1]);
  r[2] = (short)f2bf(a[2]); r[3] = (short)f2bf(a[3]);
  r[4] = (short)f2bf(b[0]); r[5] = (short)f2bf(b[1]);
  r[6] = (short)f2bf(b[2]); r[7] = (short)f2bf(b[3]);
  return r;
}
static __device__ __forceinline__ void store_out(u16* C, size_t i, float v)  { C[i] = f2bf(v); }
static __device__ __forceinline__ void store_out(float* C, size_t i, float v){ C[i] = v; }

// ---------------------------------------------------------------------------
// fp32 -> bf16 bulk convert (8 elems/thread)
// ---------------------------------------------------------------------------
__global__ __launch_bounds__(256) void f2b_kernel(
    const float* __restrict__ s, u16* __restrict__ d, int n8) {
  int i = blockIdx.x * 256 + threadIdx.x;
  if (i >= n8) return;
  *(bf16x8*)&d[(size_t)i * 8] = load8(s + (size_t)i * 8);
}

// ---------------------------------------------------------------------------
// m97-style bf16 GEMM core: C(M,N) = A(M,K)*B(N,K)^T.
// 128x128 tile, BK=64, global_load_lds width-16, XOR-swizzled unpadded LDS.
// ---------------------------------------------------------------------------
template <typename OT>
static __device__ __forceinline__ void gemm_core(
    const u16* __restrict__ A, const u16* __restrict__ B, OT* __restrict__ C,
    int K, int ldc, int bm, int bn) {
  __shared__ __align__(16) u16 As[128 * 64];
  __shared__ __align__(16) u16 Bs[128 * 64];
  const int tid  = threadIdx.x;
  const int lane = tid & 63;
  const int wave = tid >> 6;
  const int wm = (wave >> 1) << 6;
  const int wn = (wave & 1) << 6;
  const int col  = lane & 15;
  const int quad = lane >> 4;

  const f32x4 fzero = {0.f, 0.f, 0.f, 0.f};
  f32x4 acc[4][4];
#pragma unroll
  for (int i = 0; i < 4; ++i)
#pragma unroll
    for (int j = 0; j < 4; ++j) acc[i][j] = fzero;

  const int srow = (lane >> 3);
  const int sc8  = lane & 7;

  for (int k0 = 0; k0 < K; k0 += 64) {
#pragma unroll
    for (int i = 0; i < 4; ++i) {
      int r = wave * 32 + i * 8 + srow;
      int src = (sc8 ^ (r & 7)) << 3;
      gl_lds16(A + (size_t)(bm + r) * K + k0 + src, &As[(wave * 32 + i * 8) * 64]);
      gl_lds16(B + (size_t)(bn + r) * K + k0 + src, &Bs[(wave * 32 + i * 8) * 64]);
    }
    __syncthreads();
#pragma unroll
    for (int kk = 0; kk < 64; kk += 32) {
      bf16x8 af[4], bfr[4];
#pragma unroll
      for (int mt = 0; mt < 4; ++mt) {
        int row = wm + mt * 16 + col;
        af[mt] = *(const bf16x8*)&As[row * 64 + ((((kk >> 3) + quad) ^ (col & 7)) << 3)];
      }
#pragma unroll
      for (int nt = 0; nt < 4; ++nt) {
        int row = wn + nt * 16 + col;
        bfr[nt] = *(const bf16x8*)&Bs[row * 64 + ((((kk >> 3) + quad) ^ (col & 7)) << 3)];
      }
#pragma unroll
      for (int mt = 0; mt < 4; ++mt)
#pragma unroll
        for (int nt = 0; nt < 4; ++nt)
          acc[mt][nt] = __builtin_amdgcn_mfma_f32_16x16x32_bf16(
              af[mt], bfr[nt], acc[mt][nt], 0, 0, 0);
    }
    __syncthreads();
  }
#pragma unroll
  for (int mt = 0; mt < 4; ++mt)
#pragma unroll
    for (int nt = 0; nt < 4; ++nt)
#pragma unroll
      for (int r = 0; r < 4; ++r) {
        int row = bm + wm + mt * 16 + quad * 4 + r;
        int cn  = bn + wn + nt * 16 + col;
        store_out(C, (size_t)row * ldc + cn, acc[mt][nt][r]);
      }
}

__global__ __launch_bounds__(256) void gemm_qkv(
    const u16* __restrict__ xb, const u16* __restrict__ wqb,
    const u16* __restrict__ wkb, const u16* __restrict__ wvb,
    u16* __restrict__ q, u16* __restrict__ k, u16* __restrict__ v) {
  int bx = blockIdx.x;
  const u16* B; u16* C; int ldc, bn;
  if (bx < 32)      { B = wqb; C = q; ldc = 4096; bn = bx * 128; }
  else if (bx < 40) { B = wkb; C = k; ldc = 1024; bn = (bx - 32) * 128; }
  else              { B = wvb; C = v; ldc = 1024; bn = (bx - 40) * 128; }
  gemm_core<u16>(xb, B, C, 4096, ldc, blockIdx.y * 128, bn);
}

__global__ __launch_bounds__(256) void gemm_o(
    const u16* __restrict__ ao, const u16* __restrict__ wob, float* __restrict__ out) {
  gemm_core<float>(ao, wob, out, 4096, 4096, blockIdx.y * 128, blockIdx.x * 128);
}

// ---------------------------------------------------------------------------
// Fallback GEMM (fp32 staging convert, m93-class) for small workspace
// ---------------------------------------------------------------------------
#define LDK 72
template <typename AT, typename BT, typename OT>
__global__ __launch_bounds__(256) void gemm_bt(
    const AT* __restrict__ A, const BT* __restrict__ B,
    OT* __restrict__ C, int M, int N, int K) {
  __shared__ __align__(16) u16 As[128 * LDK];
  __shared__ __align__(16) u16 Bs[128 * LDK];
  const int tid  = threadIdx.x;
  const int lane = tid & 63;
  const int wave = tid >> 6;
  const int wm = (wave >> 1) << 6;
  const int wn = (wave & 1) << 6;
  const int col  = lane & 15;
  const int quad = lane >> 4;
  const int bm = blockIdx.y * 128;
  const int bn = blockIdx.x * 128;

  const f32x4 fzero = {0.f, 0.f, 0.f, 0.f};
  f32x4 acc[4][4];
#pragma unroll
  for (int i = 0; i < 4; ++i)
#pragma unroll
    for (int j = 0; j < 4; ++j) acc[i][j] = fzero;

  const int sr = tid >> 3;
  const int sc = (tid & 7) * 8;
  const AT* Aptr = A + (size_t)(bm + sr) * K + sc;
  const BT* Bptr = B + (size_t)(bn + sr) * K + sc;

  for (int k0 = 0; k0 < K; k0 += 64) {
#pragma unroll
    for (int p = 0; p < 4; ++p) {
      *(bf16x8*)&As[(sr + 32 * p) * LDK + sc] = load8(Aptr + (size_t)(32 * p) * K + k0);
      *(bf16x8*)&Bs[(sr + 32 * p) * LDK + sc] = load8(Bptr + (size_t)(32 * p) * K + k0);
    }
    __syncthreads();
#pragma unroll
    for (int kk = 0; kk < 64; kk += 32) {
      bf16x8 af[4], bfr[4];
#pragma unroll
      for (int mt = 0; mt < 4; ++mt)
        af[mt] = *(const bf16x8*)&As[(wm + mt * 16 + col) * LDK + kk + quad * 8];
#pragma unroll
      for (int nt = 0; nt < 4; ++nt)
        bfr[nt] = *(const bf16x8*)&Bs[(wn + nt * 16 + col) * LDK + kk + quad * 8];
#pragma unroll
      for (int mt = 0; mt < 4; ++mt)
#pragma unroll
        for (int nt = 0; nt < 4; ++nt)
          acc[mt][nt] = __builtin_amdgcn_mfma_f32_16x16x32_bf16(
              af[mt], bfr[nt], acc[mt][nt], 0, 0, 0);
    }
    __syncthreads();
  }
#pragma unroll
  for (int mt = 0; mt < 4; ++mt)
#pragma unroll
    for (int nt = 0; nt < 4; ++nt)
#pragma unroll
      for (int r = 0; r < 4; ++r) {
        int row = bm + wm + mt * 16 + quad * 4 + r;
        int cn  = bn + wn + nt * 16 + col;
        store_out(C, (size_t)row * N + cn, acc[mt][nt][r]);
      }
}

// ---------------------------------------------------------------------------
// RoPE in place on q (S,32,128) and k (S,8,128) bf16; scale folded into q.
// ---------------------------------------------------------------------------
__global__ __launch_bounds__(256) void rope_kernel(
    u16* __restrict__ q, u16* __restrict__ k,
    const float* __restrict__ cs, const float* __restrict__ sn) {
  int idx = blockIdx.x * 256 + threadIdx.x;
  const int QP = S_LEN * 32 * 64;
  u16* base;
  int s, i;
  bool isq = idx < QP;
  if (isq) {
    s = idx >> 11; int w = idx & 2047; i = w & 63;
    base = q + (size_t)s * 4096 + (w >> 6) * 128 + 2 * i;
  } else {
    int j = idx - QP;
    s = j >> 9; int w = j & 511; i = w & 63;
    base = k + (size_t)s * 1024 + (w >> 6) * 128 + 2 * i;
  }
  float c  = cs[s * 64 + i];
  float sv = sn[s * 64 + i];
  float x0 = bf2f(base[0]);
  float x1 = bf2f(base[1]);
  float r0 = x0 * c - x1 * sv;
  float r1 = x0 * sv + x1 * c;
  if (isq) { r0 *= ATT_SCALE; r1 *= ATT_SCALE; }
  base[0] = f2bf(r0);
  base[1] = f2bf(r1);
}

// ---------------------------------------------------------------------------
// Causal GQA flash attention, v7: 128-row q-tiles, 32 q-rows per wave
// (2 n-subtiles), so every K/V LDS read feeds TWO MFMAs -> LDS traffic
// per FLOP halved vs v6. Block = 8 waves = 2 split-K groups of 4 waves;
// tile pair {ib, 15-ib}; chunk count 2(qb+1) is even so both groups run
// qb+1 rounds; every block does exactly 17 rounds. Grid (8,32) = 256
// blocks = 1 block/CU. Bank-spread swizzle includes col>>3 so each
// lane-octet of a b128 read covers all 32 banks (matched on staging side:
// K via pre-swizzled global source, V via matching ds_write address).
// Masked softmax explicitly zeroes p (handles fully-masked chunks that
// 128-row tiles introduce). exp2-domain softmax, defer-max, setprio.
// ---------------------------------------------------------------------------
__global__ __launch_bounds__(512, 2) void attn_kernel(
    const u16* __restrict__ Q, const u16* __restrict__ K,
    const u16* __restrict__ V, u16* __restrict__ O) {
  const int ib   = blockIdx.x;       // 0..7
  const int h    = blockIdx.y;
  const int kvh  = h >> 2;
  const int tid  = threadIdx.x;
  const int lane = tid & 63;
  const int wave = tid >> 6;         // 0..7
  const int grp  = wave >> 2;        // 0..1
  const int wl   = wave & 3;         // wave within group
  const int col  = lane & 15;
  const int quad = lane >> 4;
  const int chd  = col >> 3;         // col-half, used in bank-spread swizzle
  const int gt   = tid & 255;        // thread within group

  // per-group: K chunk [64 pos][128 hd] (8192 u16) + V^T [128 hd][64 pos]
  __shared__ __align__(16) u16 SMEM[2][16384];
  __shared__ float MLS[256];
  u16* Kb = &SMEM[grp][0];
  u16* Vb = &SMEM[grp][8192];

  const f32x4 fzero = {0.f, 0.f, 0.f, 0.f};

  // staging indices
  const int krow = lane >> 4;        // K: row within 4-row issue
  const int kcnk = lane & 15;        // K: chunk slot 0..15
  const int vsc  = (gt & 15) * 8;    // V: hd group base
  const int vrp  = gt >> 4;          // V: pos-pair 0..15 (group-wide)
  const int vrot = gt & 7;

  for (int t = 0; t < 2; ++t) {
    const int qb = t ? 15 - ib : ib; // 128-row q-tile index
    const int rb = qb * 128 + wl * 32;

    // Q fragments for both 16-row subtiles (B-operand: n=q, k=quad*8+j)
    bf16x8 qf[2][4];
#pragma unroll
    for (int u = 0; u < 2; ++u)
#pragma unroll
      for (int kb = 0; kb < 4; ++kb)
        qf[u][kb] = *(const bf16x8*)&Q[(size_t)(rb + u * 16 + col) * 4096 +
                                       h * 128 + kb * 32 + quad * 8];

    // O^T accumulators: oacc[u][nt][r] at hd = nt*16 + quad*4 + r, q = col
    f32x4 oacc[2][8];
#pragma unroll
    for (int u = 0; u < 2; ++u)
#pragma unroll
      for (int nt = 0; nt < 8; ++nt) oacc[u][nt] = fzero;
    float m_[2] = {NEG_BIG, NEG_BIG};
    float l_[2] = {0.f, 0.f};

    const int nr = qb + 1;           // rounds per group (chunks = 2*nr, even)
    for (int rnd = 0; rnd < nr; ++rnd) {
      const int c    = grp * nr + rnd;
      const int pos0 = c * 64;

      // ---- stage K via global_load_lds (pre-swizzled global source)
#pragma unroll
      for (int i = 0; i < 4; ++i) {
        int r  = wl * 16 + i * 4 + krow;
        int g  = (kcnk & 8) |
                 ((((kcnk ^ r) & 7) + (((r >> 3) & 1) << 2)) & 7);
        gl_lds16(&K[(size_t)(pos0 + r) * 1024 + kvh * 128 + g * 8],
                 &Kb[(wl * 16 + i * 4) * 128]);
      }
      // ---- stage V^T: packed pos-pair b32 writes, bank-spread swizzle
#pragma unroll
      for (int it = 0; it < 2; ++it) {
        int rp = vrp + it * 16;      // pos-pair 0..31
        const u16* vp = &V[(size_t)(pos0 + 2 * rp) * 1024 + kvh * 128 + vsc];
        union { bf16x8 v; u16 u[8]; } ue, uo;
        ue.v = *(const bf16x8*)vp;
        uo.v = *(const bf16x8*)(vp + 1024);
        int pc = rp >> 2, pi = rp & 3;
#pragma unroll
        for (int j = 0; j < 8; ++j) {
          int jj = (j + vrot) & 7;
          int hd = vsc + jj;
          int swz = (((pc + (((hd >> 3) & 1) << 2)) & 7) ^ (hd & 7));
          unsigned val = (unsigned)ue.u[jj] | ((unsigned)uo.u[jj] << 16);
          *(unsigned*)&Vb[hd * 64 + swz * 8 + pi * 2] = val;
        }
      }
      __syncthreads();

      // ---- S^T = K Q^T : each kf read feeds both q-subtiles
      f32x4 sv[2][4];
#pragma unroll
      for (int u = 0; u < 2; ++u)
#pragma unroll
        for (int kv = 0; kv < 4; ++kv) sv[u][kv] = fzero;
      __builtin_amdgcn_s_setprio(1);
#pragma unroll
      for (int kv = 0; kv < 4; ++kv) {
        int r = kv * 16 + col;
#pragma unroll
        for (int kb = 0; kb < 4; ++kb) {
          int kq   = kb * 4 + quad;
          int slot = (kq & 8) | ((((kq & 7) + (chd << 2)) & 7) ^ (r & 7));
          bf16x8 kf = *(const bf16x8*)&Kb[r * 128 + slot * 8];
          sv[0][kv] = __builtin_amdgcn_mfma_f32_16x16x32_bf16(kf, qf[0][kv*0+kb], sv[0][kv], 0, 0, 0);
          sv[1][kv] = __builtin_amdgcn_mfma_f32_16x16x32_bf16(kf, qf[1][kb], sv[1][kv], 0, 0, 0);
        }
      }
      __builtin_amdgcn_s_setprio(0);

      // ---- softmax per subtile (exp2 domain, defer-max, masked p -> 0)
      unsigned pk[2][4][2];
#pragma unroll
      for (int u = 0; u < 2; ++u) {
        const int ubase = rb + u * 16;
        const int qpos  = ubase + col;
        const bool nomask = (pos0 + 63 <= ubase);
        float mx = NEG_BIG;
        if (nomask) {
#pragma unroll
          for (int kv = 0; kv < 4; ++kv)
#pragma unroll
            for (int r = 0; r < 4; ++r) mx = fmaxf(mx, sv[u][kv][r]);
        } else {
#pragma unroll
          for (int kv = 0; kv < 4; ++kv)
#pragma unroll
            for (int r = 0; r < 4; ++r) {
              bool keep = (pos0 + kv * 16 + quad * 4 + r) <= qpos;
              float s = keep ? sv[u][kv][r] : NEG_BIG;
              sv[u][kv][r] = s;
              mx = fmaxf(mx, s);
            }
        }
        mx = fmaxf(mx, __shfl_xor(mx, 16));
        mx = fmaxf(mx, __shfl_xor(mx, 32));
        if (!__all(mx - m_[u] <= 8.f)) {
          float mnew  = fmaxf(m_[u], mx);
          float alpha = fexp2(m_[u] - mnew);
          l_[u] *= alpha;
#pragma unroll
          for (int nt = 0; nt < 8; ++nt) {
            oacc[u][nt][0] *= alpha; oacc[u][nt][1] *= alpha;
            oacc[u][nt][2] *= alpha; oacc[u][nt][3] *= alpha;
          }
          m_[u] = mnew;
        }
        float ls = 0.f;
        if (nomask) {
#pragma unroll
          for (int kv = 0; kv < 4; ++kv)
#pragma unroll
            for (int r = 0; r < 4; ++r) {
              float p = fexp2(sv[u][kv][r] - m_[u]);
              sv[u][kv][r] = p;
              ls += p;
            }
        } else {
#pragma unroll
          for (int kv = 0; kv < 4; ++kv)
#pragma unroll
            for (int r = 0; r < 4; ++r) {
              float p = fexp2(sv[u][kv][r] - m_[u]);
              bool keep = (pos0 + kv * 16 + quad * 4 + r) <= qpos;
              p = keep ? p : 0.f;   // robust even when m_ is still NEG_BIG
              sv[u][kv][r] = p;
              ls += p;
            }
        }
        ls += __shfl_xor(ls, 16);
        ls += __shfl_xor(ls, 32);
        l_[u] += ls;
        // pack P^T tiles: pk[u][kv][hh] = bf16x2(p[2hh], p[2hh+1])
#pragma unroll
        for (int kv = 0; kv < 4; ++kv) {
          pk[u][kv][0] = (unsigned)f2bf(sv[u][kv][0]) | ((unsigned)f2bf(sv[u][kv][1]) << 16);
          pk[u][kv][1] = (unsigned)f2bf(sv[u][kv][2]) | ((unsigned)f2bf(sv[u][kv][3]) << 16);
        }
      }

      // ---- O^T += V^T P^T : each vf read feeds both q-subtiles
      const int idxA = col + 16 * (2 * (quad & 1));
      const int idxB = idxA + 16;
      const bool hi  = quad >= 2;
#pragma unroll
      for (int kc = 0; kc < 2; ++kc) {
        union { unsigned u[4]; bf16x8 v; } pb[2];
#pragma unroll
        for (int u = 0; u < 2; ++u) {
          unsigned a00 = __shfl(pk[u][2 * kc][0],     idxA);
          unsigned a01 = __shfl(pk[u][2 * kc][1],     idxA);
          unsigned a10 = __shfl(pk[u][2 * kc + 1][0], idxA);
          unsigned a11 = __shfl(pk[u][2 * kc + 1][1], idxA);
          unsigned b00 = __shfl(pk[u][2 * kc][0],     idxB);
          unsigned b01 = __shfl(pk[u][2 * kc][1],     idxB);
          unsigned b10 = __shfl(pk[u][2 * kc + 1][0], idxB);
          unsigned b11 = __shfl(pk[u][2 * kc + 1][1], idxB);
          pb[u].u[0] = hi ? a10 : a00;
          pb[u].u[1] = hi ? a11 : a01;
          pb[u].u[2] = hi ? b10 : b00;
          pb[u].u[3] = hi ? b11 : b01;
        }
        __builtin_amdgcn_s_setprio(1);
#pragma unroll
        for (int nt = 0; nt < 8; ++nt) {
          int hd  = nt * 16 + col;
          int pc  = kc * 4 + quad;
          int swz = (((pc + (chd << 2)) & 7) ^ (hd & 7));
          bf16x8 vf = *(const bf16x8*)&Vb[hd * 64 + swz * 8];
          oacc[0][nt] = __builtin_amdgcn_mfma_f32_16x16x32_bf16(vf, pb[0].v, oacc[0][nt], 0, 0, 0);
          oacc[1][nt] = __builtin_amdgcn_mfma_f32_16x16x32_bf16(vf, pb[1].v, oacc[1][nt], 0, 0, 0);
        }
        __builtin_amdgcn_s_setprio(0);
      }
      __syncthreads();
    }

    // ---- cross-group merge via LDS (reuses staging space), then store
    float* MF = (float*)&SMEM[0][0];       // [128 q][128 hd] f32 = 64KB
    if (grp == 1) {
#pragma unroll
      for (int u = 0; u < 2; ++u) {
        int ql = wl * 32 + u * 16 + col;
#pragma unroll
        for (int nt = 0; nt < 8; ++nt)
          *(f32x4*)&MF[(size_t)ql * 128 + nt * 16 + quad * 4] = oacc[u][nt];
        if (quad == 0) { MLS[2 * ql] = m_[u]; MLS[2 * ql + 1] = l_[u]; }
      }
    }
    __syncthreads();
    if (grp == 0) {
#pragma unroll
      for (int u = 0; u < 2; ++u) {
        int ql = wl * 32 + u * 16 + col;
        int qpos = qb * 128 + ql;
        float m1 = MLS[2 * ql], l1 = MLS[2 * ql + 1];
        float mn = fmaxf(m_[u], m1);
        float a0 = fexp2(m_[u] - mn), a1 = fexp2(m1 - mn);
        float li = 1.f / (l_[u] * a0 + l1 * a1);
        a0 *= li; a1 *= li;
#pragma unroll
        for (int nt = 0; nt < 8; ++nt) {
          f32x4 o1 = *(const f32x4*)&MF[(size_t)ql * 128 + nt * 16 + quad * 4];
          union { u16 u[4]; unsigned long long ll; } w;
          w.u[0] = f2bf(oacc[u][nt][0] * a0 + o1[0] * a1);
          w.u[1] = f2bf(oacc[u][nt][1] * a0 + o1[1] * a1);
          w.u[2] = f2bf(oacc[u][nt][2] * a0 + o1[2] * a1);
          w.u[3] = f2bf(oacc[u][nt][3] * a0 + o1[3] * a1);
          *(unsigned long long*)&O[(size_t)qpos * 4096 + h * 128 + nt * 16 + quad * 4] = w.ll;
        }
      }
    }
    __syncthreads();
  }
}

// ---------------------------------------------------------------------------
extern "C" void kernel_launch(void* const* d_in, const int* in_sizes, int n_in,
                              void* d_out, int out_size, void* d_ws, size_t ws_size,
                              hipStream_t stream) {
  const float* x  = (const float*)d_in[0];
  const float* fc = (const float*)d_in[1];
  const float* fs = (const float*)d_in[2];
  const float* wq = (const float*)d_in[3];
  const float* wk = (const float*)d_in[4];
  const float* wv = (const float*)d_in[5];
  const float* wo = (const float*)d_in[6];
  float* out = (float*)d_out;

  u16* q  = (u16*)d_ws;                      // 2048*4096
  u16* k  = q + (size_t)8388608;             // 2048*1024
  u16* v  = k + (size_t)2097152;
  u16* ao = v + (size_t)2097152;             // 2048*4096

  dim3 blk(256, 1, 1);
  dim3 ablk(512, 1, 1);
  const size_t NEED_FAST = 109051904ULL;     // bytes

  if (ws_size >= NEED_FAST) {
    u16* xb  = ao  + (size_t)8388608;        // 2048*4096
    u16* wqb = xb  + (size_t)8388608;        // 4096*4096
    u16* wkb = wqb + (size_t)16777216;       // 1024*4096
    u16* wvb = wkb + (size_t)4194304;        // 1024*4096
    u16* wob = wqb;                          // reuse after QKV GEMM

    hipLaunchKernelGGL(f2b_kernel, dim3(4096, 1, 1), blk, 0, stream, x,  xb,  1048576);
    hipLaunchKernelGGL(f2b_kernel, dim3(8192, 1, 1), blk, 0, stream, wq, wqb, 2097152);
    hipLaunchKernelGGL(f2b_kernel, dim3(2048, 1, 1), blk, 0, stream, wk, wkb, 524288);
    hipLaunchKernelGGL(f2b_kernel, dim3(2048, 1, 1), blk, 0, stream, wv, wvb, 524288);
    hipLaunchKernelGGL(gemm_qkv, dim3(48, 16, 1), blk, 0, stream, xb, wqb, wkb, wvb, q, k, v);
    hipLaunchKernelGGL(f2b_kernel, dim3(8192, 1, 1), blk, 0, stream, wo, wob, 2097152);
    hipLaunchKernelGGL(rope_kernel, dim3(20480, 1, 1), blk, 0, stream, q, k, fc, fs);
    hipLaunchKernelGGL(attn_kernel, dim3(8, 32, 1), ablk, 0, stream, q, k, v, ao);
    hipLaunchKernelGGL(gemm_o, dim3(32, 16, 1), blk, 0, stream, ao, wob, out);
  } else {
    hipLaunchKernelGGL((gemm_bt<float, float, u16>), dim3(32, 16, 1), blk, 0, stream,
                       x, wq, q, 2048, 4096, 4096);
    hipLaunchKernelGGL((gemm_bt<float, float, u16>), dim3(8, 16, 1),  blk, 0, stream,
                       x, wk, k, 2048, 1024, 4096);
    hipLaunchKernelGGL((gemm_bt<float, float, u16>), dim3(8, 16, 1),  blk, 0, stream,
                       x, wv, v, 2048, 1024, 4096);
    hipLaunchKernelGGL(rope_kernel, dim3(20480, 1, 1), blk, 0, stream, q, k, fc, fs);
    hipLaunchKernelGGL(attn_kernel, dim3(8, 32, 1), ablk, 0, stream, q, k, v, ao);
    hipLaunchKernelGGL((gemm_bt<u16, float, float>), dim3(32, 16, 1), blk, 0, stream,
                       ao, wo, out, 2048, 4096, 4096);
  }
}